// Round 13
// baseline (2565.741 us; speedup 1.0000x reference)
//
#include <hip/hip_runtime.h>
#include <hip/hip_bf16.h>
#include <float.h>

// Problem constants (from reference setup_inputs)
#define B_   4
#define N_   4096
#define J_   24
#define KR_  4
#define KNN_ 20
#define SLOPE 0.2f
#define SLABN 64             // points per pooling slab
#define NSLAB (N_ / SLABN)   // 64
#define NTILE 32             // 128-wide tiles per dim

// ---------- per-point squared norm ----------
__global__ void k_norm(const float* __restrict__ h, float* __restrict__ xx, int C) {
    int i = blockIdx.x * blockDim.x + threadIdx.x;
    if (i >= B_ * N_) return;
    const float* hp = h + (size_t)i * C;
    float s = 0.f;
    for (int c = 0; c < C; ++c) { float v = hp[c]; s += v * v; }
    xx[i] = s;
}

// ---------- symmetric distance GEMM: upper-triangular tiles only ----------
__global__ __launch_bounds__(256) void k_dist(const float* __restrict__ X, int C,
                                              const float* __restrict__ xxb,
                                              float* __restrict__ D) {
    __shared__ float As[16][132];
    __shared__ float Bs[16][132];
    int t = blockIdx.x;                      // linear upper-tri tile id
    int ti = 0;
    while (t >= NTILE - ti) { t -= NTILE - ti; ++ti; }
    int tj = ti + t;
    int row0 = ti * 128, col0 = tj * 128;
    int tid = threadIdx.x;
    int tr = tid >> 4, tc = tid & 15;
    float acc[8][8] = {{0.f}};
    for (int kt = 0; kt < C; kt += 16) {
#pragma unroll
        for (int i = 0; i < 8; ++i) {
            int e = tid + 256 * i;
            int r = e >> 4, kk = e & 15;
            int gk = kt + kk;
            As[kk][r] = (gk < C) ? X[(size_t)(row0 + r) * C + gk] : 0.f;
            Bs[kk][r] = (gk < C) ? X[(size_t)(col0 + r) * C + gk] : 0.f;
        }
        __syncthreads();
#pragma unroll
        for (int kk = 0; kk < 16; ++kk) {
            float a[8], bv[8];
            *(float4*)&a[0]  = *(const float4*)&As[kk][tr * 4];
            *(float4*)&a[4]  = *(const float4*)&As[kk][64 + tr * 4];
            *(float4*)&bv[0] = *(const float4*)&Bs[kk][tc * 4];
            *(float4*)&bv[4] = *(const float4*)&Bs[kk][64 + tc * 4];
#pragma unroll
            for (int i = 0; i < 8; ++i)
#pragma unroll
                for (int j = 0; j < 8; ++j) acc[i][j] += a[i] * bv[j];
        }
        __syncthreads();
    }
    float xc[8], xr[8];
#pragma unroll
    for (int j = 0; j < 4; ++j) {
        xc[j]     = xxb[col0 + tc * 4 + j];
        xc[4 + j] = xxb[col0 + 64 + tc * 4 + j];
        xr[j]     = xxb[row0 + tr * 4 + j];
        xr[4 + j] = xxb[row0 + 64 + tr * 4 + j];
    }
#pragma unroll
    for (int i = 0; i < 8; ++i) {
        int lr = (i < 4) ? (tr * 4 + i) : (64 + tr * 4 + (i - 4));
        float xri = xr[i];
        float4 o0, o1;
        o0.x = xri + xc[0] - 2.f * acc[i][0];
        o0.y = xri + xc[1] - 2.f * acc[i][1];
        o0.z = xri + xc[2] - 2.f * acc[i][2];
        o0.w = xri + xc[3] - 2.f * acc[i][3];
        o1.x = xri + xc[4] - 2.f * acc[i][4];
        o1.y = xri + xc[5] - 2.f * acc[i][5];
        o1.z = xri + xc[6] - 2.f * acc[i][6];
        o1.w = xri + xc[7] - 2.f * acc[i][7];
        float* dp = D + (size_t)(row0 + lr) * N_ + col0;
        *(float4*)(dp + tc * 4)      = o0;
        *(float4*)(dp + 64 + tc * 4) = o1;
    }
    if (ti == tj) return;
    // mirrored store via LDS transpose, 4 passes of 32 dt-rows
    float* tb = &As[0][0];
    for (int p = 0; p < 4; ++p) {
        __syncthreads();
        int h = p >> 1;
        int tclo = (p & 1) * 8;
        if (tc >= tclo && tc < tclo + 8) {
#pragma unroll
            for (int jj = 0; jj < 4; ++jj) {
                int j = h * 4 + jj;
                int cl = h * 64 + tc * 4 + jj - 32 * p;   // 0..31
                float xcj = xc[j];
                float4 vlo, vhi;
                vlo.x = xr[0] + xcj - 2.f * acc[0][j];
                vlo.y = xr[1] + xcj - 2.f * acc[1][j];
                vlo.z = xr[2] + xcj - 2.f * acc[2][j];
                vlo.w = xr[3] + xcj - 2.f * acc[3][j];
                vhi.x = xr[4] + xcj - 2.f * acc[4][j];
                vhi.y = xr[5] + xcj - 2.f * acc[5][j];
                vhi.z = xr[6] + xcj - 2.f * acc[6][j];
                vhi.w = xr[7] + xcj - 2.f * acc[7][j];
                *(float4*)&tb[cl * 132 + tr * 4]      = vlo;
                *(float4*)&tb[cl * 132 + 64 + tr * 4] = vhi;
            }
        }
        __syncthreads();
        int rl  = tid >> 3;
        int c16 = (tid & 7) * 16;
#pragma unroll
        for (int q = 0; q < 4; ++q) {
            float4 v = *(const float4*)&tb[rl * 132 + c16 + q * 4];
            *(float4*)(D + (size_t)(col0 + 32 * p + rl) * N_ + row0 + c16 + q * 4) = v;
        }
    }
}

// ---------- key mapping: monotone f32 -> u32 ----------
__device__ __forceinline__ unsigned mapf(float f) {
    unsigned u = __float_as_uint(f);
    return (u & 0x80000000u) ? ~u : (u | 0x80000000u);
}

// ---------- in-lane top-2 maintenance (strict < keeps smallest index first) ----------
__device__ __forceinline__ void top2_upd(unsigned kv, unsigned ki,
                                         unsigned& b0v, unsigned& b0i,
                                         unsigned& b1v, unsigned& b1i) {
    if (kv < b1v) {
        if (kv < b0v) { b1v = b0v; b1i = b0i; b0v = kv; b0i = ki; }
        else          { b1v = kv;  b1i = ki; }
    }
}

// ---------- top-20 selection: ONE WAVE PER ROW (4 rows per block) ----------
// Lane owns 64 contiguous cols; top-2/lane in registers; per pop: u32 value
// butterfly + u32 index butterfly (exact (value,index) lexicographic order).
__global__ __launch_bounds__(256) void k_sel(const float* __restrict__ Db,
                                             int* __restrict__ idxout) {
    const unsigned INV = 0xFFFFFFFFu;
    int q    = blockIdx.x * 4 + (threadIdx.x >> 6);
    int lane = threadIdx.x & 63;
    int gbase = lane * 64;
    const float* seg = Db + (size_t)q * N_ + gbase;

    unsigned b0v = INV, b0i = INV, b1v = INV, b1i = INV;
    unsigned long long emask = 0;
#pragma unroll
    for (int t = 0; t < 64; t += 4) {
        float4 v = *(const float4*)(seg + t);
        top2_upd(mapf(v.x), (unsigned)(gbase + t),     b0v, b0i, b1v, b1i);
        top2_upd(mapf(v.y), (unsigned)(gbase + t + 1), b0v, b0i, b1v, b1i);
        top2_upd(mapf(v.z), (unsigned)(gbase + t + 2), b0v, b0i, b1v, b1i);
        top2_upd(mapf(v.w), (unsigned)(gbase + t + 3), b0v, b0i, b1v, b1i);
    }
    for (int k = 0; k < KNN_; ++k) {
        if (b0i == INV) {                       // rare refill: rescan my 64 (L2-hot)
            b0v = INV; b1v = INV; b1i = INV;
            for (int t = 0; t < 64; ++t) {
                if ((emask >> t) & 1ull) continue;
                top2_upd(mapf(seg[t]), (unsigned)(gbase + t), b0v, b0i, b1v, b1i);
            }
        }
        unsigned vm = b0v;
#pragma unroll
        for (int s = 32; s > 0; s >>= 1) {
            unsigned o = (unsigned)__shfl_xor((int)vm, s, 64);
            vm = (o < vm) ? o : vm;
        }
        unsigned im = (b0v == vm) ? b0i : INV;  // min index among tied values
#pragma unroll
        for (int s = 32; s > 0; s >>= 1) {
            unsigned o = (unsigned)__shfl_xor((int)im, s, 64);
            im = (o < im) ? o : im;
        }
        if (b0v == vm && b0i == im) {           // unique owner pops
            emask |= 1ull << (b0i & 63u);
            b0v = b1v; b0i = b1i; b1v = INV; b1i = INV;
        }
        if (lane == 0) idxout[q * KNN_ + k] = (int)im;
    }
}

// ---------- layer-1 fused dist+select (C=3), one wave per row, all batches ----------
__global__ __launch_bounds__(256) void k_selC3(const float* __restrict__ V,
                                               const float* __restrict__ xx,
                                               int* __restrict__ knnIdx) {
    const unsigned INV = 0xFFFFFFFFu;
    int b    = blockIdx.y;
    const float* Xb  = V + (size_t)b * N_ * 3;
    const float* xxb = xx + (size_t)b * N_;
    int* idxout = knnIdx + (size_t)b * N_ * KNN_;
    int q    = blockIdx.x * 4 + (threadIdx.x >> 6);
    int lane = threadIdx.x & 63;
    int gbase = lane * 64;

    float qx = Xb[q * 3], qy = Xb[q * 3 + 1], qz = Xb[q * 3 + 2];
    float xxq = xxb[q];

    unsigned b0v = INV, b0i = INV, b1v = INV, b1i = INV;
    unsigned long long emask = 0;
    for (int c = 0; c < 64; c += 16) {          // 4 chunks of 16 points
        float p[48], xm[16];
        const float4* ps = (const float4*)(Xb + (size_t)(gbase + c) * 3);
#pragma unroll
        for (int t = 0; t < 12; ++t) ((float4*)p)[t] = ps[t];
        const float4* xs = (const float4*)(xxb + gbase + c);
#pragma unroll
        for (int t = 0; t < 4; ++t) ((float4*)xm)[t] = xs[t];
#pragma unroll
        for (int t = 0; t < 16; ++t) {
            float dot = qx * p[3 * t];
            dot = fmaf(qy, p[3 * t + 1], dot);
            dot = fmaf(qz, p[3 * t + 2], dot);
            float d = xxq + xm[t] - 2.f * dot;
            top2_upd(mapf(d), (unsigned)(gbase + c + t), b0v, b0i, b1v, b1i);
        }
    }
    for (int k = 0; k < KNN_; ++k) {
        if (b0i == INV) {                       // rare refill: recompute (same fma order)
            b0v = INV; b1v = INV; b1i = INV;
            for (int c = 0; c < 64; c += 16) {
                float p[48], xm[16];
                const float4* ps = (const float4*)(Xb + (size_t)(gbase + c) * 3);
#pragma unroll
                for (int t = 0; t < 12; ++t) ((float4*)p)[t] = ps[t];
                const float4* xs = (const float4*)(xxb + gbase + c);
#pragma unroll
                for (int t = 0; t < 4; ++t) ((float4*)xm)[t] = xs[t];
#pragma unroll
                for (int t = 0; t < 16; ++t) {
                    if ((emask >> (c + t)) & 1ull) continue;
                    float dot = qx * p[3 * t];
                    dot = fmaf(qy, p[3 * t + 1], dot);
                    dot = fmaf(qz, p[3 * t + 2], dot);
                    float d = xxq + xm[t] - 2.f * dot;
                    top2_upd(mapf(d), (unsigned)(gbase + c + t), b0v, b0i, b1v, b1i);
                }
            }
        }
        unsigned vm = b0v;
#pragma unroll
        for (int s = 32; s > 0; s >>= 1) {
            unsigned o = (unsigned)__shfl_xor((int)vm, s, 64);
            vm = (o < vm) ? o : vm;
        }
        unsigned im = (b0v == vm) ? b0i : INV;
#pragma unroll
        for (int s = 32; s > 0; s >>= 1) {
            unsigned o = (unsigned)__shfl_xor((int)im, s, 64);
            im = (o < im) ? o : im;
        }
        if (b0v == vm && b0i == im) {
            emask |= 1ull << (b0i & 63u);
            b0v = b1v; b0i = b1i; b1v = INV; b1i = INV;
        }
        if (lane == 0) idxout[q * KNN_ + k] = (int)im;
    }
}

// ---------- fused weight prep ----------
__device__ __forceinline__ void prepP_elem(const float* __restrict__ w,
                                           const float* __restrict__ bias,
                                           int C, int O, float* __restrict__ P,
                                           float* __restrict__ b2, int i) {
    int O2 = 2 * O;
    if (i < O2) b2[i] = (i < O) ? 0.f : bias[i - O];
    if (i >= C * O2) return;
    int k = i / O2, col = i % O2;
    float v;
    if (col < O) v = w[(size_t)col * 2 * C + k];
    else { int o = col - O; v = w[(size_t)o * 2 * C + C + k] - w[(size_t)o * 2 * C + k]; }
    P[i] = v;
}
__device__ __forceinline__ void transp_elem(const float* __restrict__ w, int O, int K,
                                            float* __restrict__ wT, int i) {
    if (i >= O * K) return;
    int k = i / O, o = i % O;
    wT[i] = w[(size_t)o * K + k];
}

__global__ void k_prepall(const float* g1w, const float* g1b,
                          const float* g2w, const float* g2b,
                          const float* g3w, const float* g3b,
                          const float* s1w, const float* s1b,
                          const float* s2w, const float* s2b,
                          const float* s3w, const float* s3b,
                          const float* m1w, const float* m2w, const float* m3w,
                          float* P1, float* P2, float* P3, float* P4, float* P5,
                          float* P6, float* P7, float* P8, float* P9,
                          float* bb1, float* bb2, float* bb3,
                          float* bb4, float* bb5, float* bb6) {
    int i = blockIdx.x * 256 + threadIdx.x;
    switch (blockIdx.y) {
        case 0: prepP_elem(g1w, g1b, 3,   64,  P1, bb1, i); break;
        case 1: prepP_elem(g2w, g2b, 64,  128, P2, bb2, i); break;
        case 2: prepP_elem(g3w, g3b, 128, 256, P3, bb3, i); break;
        case 3: prepP_elem(s1w, s1b, 451, 256, P4, bb4, i); break;
        case 4: prepP_elem(s2w, s2b, 256, 128, P5, bb5, i); break;
        case 5: prepP_elem(s3w, s3b, 128, 64,  P6, bb6, i); break;
        case 6: transp_elem(m1w, 512, 448, P7, i); break;
        case 7: transp_elem(m2w, 256, 512, P8, i); break;
        case 8: transp_elem(m3w, 3,   256, P9, i); break;
    }
}

// ---------- tiled f32 GEMM (large M) ----------
__global__ __launch_bounds__(256) void k_gemm(const float* __restrict__ A, int lda,
                                              const float* __restrict__ Bm,
                                              float* __restrict__ Cm, int ldc,
                                              int M, int N, int K,
                                              const float* __restrict__ bias, int leaky) {
    __shared__ float As[16][68];
    __shared__ float Bs[16][68];
    int tid = threadIdx.x;
    int row0 = blockIdx.y * 64, col0 = blockIdx.x * 64;
    int tr = tid >> 4, tc = tid & 15;
    float acc[4][4] = {{0.f}};
    for (int kt = 0; kt < K; kt += 16) {
#pragma unroll
        for (int i = 0; i < 4; ++i) {
            int e = tid + 256 * i;
            int r = e >> 4, kk = e & 15;
            int gr = row0 + r, gk = kt + kk;
            float v = 0.f;
            if (gr < M && gk < K) v = A[(size_t)gr * lda + gk];
            As[kk][r] = v;
        }
#pragma unroll
        for (int i = 0; i < 4; ++i) {
            int e = tid + 256 * i;
            int kk = e >> 6, c = e & 63;
            int gk = kt + kk, gc = col0 + c;
            float v = 0.f;
            if (gk < K && gc < N) v = Bm[(size_t)gk * N + gc];
            Bs[kk][c] = v;
        }
        __syncthreads();
#pragma unroll
        for (int kk = 0; kk < 16; ++kk) {
            float a[4], bv[4];
            *(float4*)&a[0]  = *(const float4*)&As[kk][tr * 4];
            *(float4*)&bv[0] = *(const float4*)&Bs[kk][tc * 4];
#pragma unroll
            for (int i = 0; i < 4; ++i)
#pragma unroll
                for (int j = 0; j < 4; ++j) acc[i][j] += a[i] * bv[j];
        }
        __syncthreads();
    }
#pragma unroll
    for (int i = 0; i < 4; ++i) {
        int r = row0 + tr * 4 + i;
        if (r >= M) continue;
#pragma unroll
        for (int j = 0; j < 4; ++j) {
            int c = col0 + tc * 4 + j;
            if (c >= N) continue;
            float v = acc[i][j];
            if (bias) v += bias[c];
            if (leaky) v = v >= 0.f ? v : SLOPE * v;
            Cm[(size_t)r * ldc + c] = v;
        }
    }
}

// ---------- small-M GEMM ----------
__global__ __launch_bounds__(256) void k_sgemm(const float* __restrict__ A, int lda,
                                               const float* __restrict__ Bm,
                                               float* __restrict__ Cm, int ldc,
                                               int N, int K,
                                               const float* __restrict__ bias, int leaky) {
    extern __shared__ float Arow[];
    int r   = blockIdx.x;
    int c0  = blockIdx.y * 256;
    int tid = threadIdx.x;
    for (int k = tid; k < K; k += 256) Arow[k] = A[(size_t)r * lda + k];
    __syncthreads();
    int c = c0 + tid;
    if (c >= N) return;
    float acc = bias ? bias[c] : 0.f;
    for (int k = 0; k < K; ++k) acc += Arow[k] * Bm[(size_t)k * N + c];
    if (leaky) acc = acc >= 0.f ? acc : SLOPE * acc;
    Cm[(size_t)r * ldc + c] = acc;
}

// ---------- gather-max epilogue (+ optional fused row-norm) ----------
__global__ void k_gathermax(const float* __restrict__ Y, int O, int R,
                            const int* __restrict__ idx, int kc,
                            float* __restrict__ out, int ldo, int ooff,
                            float* __restrict__ xxout) {
    extern __shared__ int sidx[];
    __shared__ float red[256];
    int br = blockIdx.x;
    int b  = br / R;
    int o  = threadIdx.x;
    if (o < kc) sidx[o] = idx[(size_t)br * kc + o];
    __syncthreads();
    int O2 = 2 * O;
    float z = Y[(size_t)br * O2 + O + o];
    float best = -FLT_MAX;
    for (int k = 0; k < kc; ++k) {
        int m = sidx[k];
        best = fmaxf(best, Y[(size_t)(b * R + m) * O2 + o]);
    }
    float r = z + best;
    r = r >= 0.f ? r : SLOPE * r;
    out[(size_t)br * ldo + ooff + o] = r;
    if (xxout) {
        red[o] = r * r;
        __syncthreads();
        for (int s = blockDim.x >> 1; s > 0; s >>= 1) {
            if (o < s) red[o] += red[o + s];
            __syncthreads();
        }
        if (o == 0) xxout[br] = red[0];
    }
}

// ---------- channel map ----------
__device__ __forceinline__ void chan_map(int b, int c,
                                         const float* Vf, const float* l1,
                                         const float* l2, const float* l3,
                                         const float*& p, int& st) {
    if (c < 3)        { st = 3;   p = Vf + (size_t)b * N_ * 3   + c; }
    else if (c < 67)  { st = 64;  p = l1 + (size_t)b * N_ * 64  + (c - 3); }
    else if (c < 195) { st = 128; p = l2 + (size_t)b * N_ * 128 + (c - 67); }
    else              { st = 256; p = l3 + (size_t)b * N_ * 256 + (c - 195); }
}

// ---------- pooling phase 1 ----------
__global__ __launch_bounds__(256) void k_pool2(const float* __restrict__ Vf,
                                               const float* __restrict__ l1,
                                               const float* __restrict__ l2,
                                               const float* __restrict__ l3,
                                               const float* __restrict__ W,
                                               float* __restrict__ ppool,
                                               float* __restrict__ psw) {
    __shared__ float Wl[SLABN][J_];
    int blk  = blockIdx.x;
    int b    = blk / NSLAB, slab = blk % NSLAB;
    int n0   = slab * SLABN;
    int tid  = threadIdx.x;

    for (int e = tid; e < J_ * SLABN; e += 256) {
        int j = e / SLABN, n = e % SLABN;
        Wl[n][j] = W[((size_t)b * J_ + j) * N_ + n0 + n];
    }
    __syncthreads();

    if (tid < J_) {
        float s = 0.f;
        for (int n = 0; n < SLABN; ++n) s += Wl[n][tid];
        psw[(size_t)blk * J_ + tid] = s;
    }

    int c0 = tid, c1 = tid + 256;
    const float *p0, *p1 = nullptr; int s0, s1 = 0;
    chan_map(b, c0, Vf, l1, l2, l3, p0, s0);
    bool has1 = (c1 < 451);
    if (has1) chan_map(b, c1, Vf, l1, l2, l3, p1, s1);

    float acc0[J_], acc1[J_];
#pragma unroll
    for (int j = 0; j < J_; ++j) { acc0[j] = 0.f; acc1[j] = 0.f; }

    for (int n = 0; n < SLABN; ++n) {
        float v0 = p0[(size_t)(n0 + n) * s0];
        float v1 = has1 ? p1[(size_t)(n0 + n) * s1] : 0.f;
        const float* wn = &Wl[n][0];
#pragma unroll
        for (int q = 0; q < J_ / 4; ++q) {
            float4 w4 = *(const float4*)(wn + 4 * q);
            acc0[4*q+0] += w4.x * v0;  acc1[4*q+0] += w4.x * v1;
            acc0[4*q+1] += w4.y * v0;  acc1[4*q+1] += w4.y * v1;
            acc0[4*q+2] += w4.z * v0;  acc1[4*q+2] += w4.z * v1;
            acc0[4*q+3] += w4.w * v0;  acc1[4*q+3] += w4.w * v1;
        }
    }
    float* pp = ppool + (size_t)blk * J_ * 451;
#pragma unroll
    for (int j = 0; j < J_; ++j) {
        pp[(size_t)j * 451 + c0] = acc0[j];
        if (has1) pp[(size_t)j * 451 + c1] = acc1[j];
    }
}

// ---------- pooling phase 2 ----------
__global__ __launch_bounds__(256) void k_poolred(const float* __restrict__ ppool,
                                                 const float* __restrict__ psw,
                                                 float* __restrict__ pooled) {
    int bj = blockIdx.x;
    int b  = bj / J_, j = bj % J_;
    int tid = threadIdx.x;

    float sw = 0.f;
    for (int sl = 0; sl < NSLAB; ++sl) sw += psw[(size_t)(b * NSLAB + sl) * J_ + j];
    float inv = 1.f / (sw + 1e-5f);

    for (int c = tid; c < 451; c += 256) {
        float s = 0.f;
        for (int sl = 0; sl < NSLAB; ++sl)
            s += ppool[((size_t)(b * NSLAB + sl) * J_ + j) * 451 + c];
        pooled[(size_t)bj * 451 + c] = s * inv;
    }
}

extern "C" void kernel_launch(void* const* d_in, const int* in_sizes, int n_in,
                              void* d_out, int out_size, void* d_ws, size_t ws_size,
                              hipStream_t stream) {
    const float* V  = (const float*)d_in[0];
    const float* W  = (const float*)d_in[1];
    const int* ringIdx = (const int*)d_in[2];
    const float* g1w = (const float*)d_in[3];
    const float* g1b = (const float*)d_in[4];
    const float* g2w = (const float*)d_in[5];
    const float* g2b = (const float*)d_in[6];
    const float* g3w = (const float*)d_in[7];
    const float* g3b = (const float*)d_in[8];
    const float* s1w = (const float*)d_in[9];
    const float* s1b = (const float*)d_in[10];
    const float* s2w = (const float*)d_in[11];
    const float* s2b = (const float*)d_in[12];
    const float* s3w = (const float*)d_in[13];
    const float* s3b = (const float*)d_in[14];
    const float* m1w = (const float*)d_in[15];
    const float* m1b = (const float*)d_in[16];
    const float* m2w = (const float*)d_in[17];
    const float* m2b = (const float*)d_in[18];
    const float* m3w = (const float*)d_in[19];
    const float* m3b = (const float*)d_in[20];
    (void)n_in; (void)in_sizes; (void)out_size; (void)ws_size;

    const int szP1 = 3 * 128,    szP2 = 64 * 256,  szP3 = 128 * 512;
    const int szP4 = 451 * 512,  szP5 = 256 * 256, szP6 = 128 * 128;
    const int szP7 = 448 * 512,  szP8 = 512 * 256, szP9 = 256 * 3;

    // ---- workspace layout (floats); D = full N x N (64 MB, proven fit) ----
    float* ws = (float*)d_ws;
    size_t off = 0;
    float* l1 = ws + off; off += (size_t)B_ * N_ * 64;
    float* l2 = ws + off; off += (size_t)B_ * N_ * 128;
    float* l3 = ws + off; off += (size_t)B_ * N_ * 256;
    float* xx = ws + off; off += (size_t)B_ * N_;
    float* D  = ws + off; off += (size_t)N_ * N_;
    float* Y  = D;
    float* ppool = D;
    float* psw   = D + (size_t)B_ * NSLAB * J_ * 451;
    int* knnIdx = (int*)(ws + off); off += (size_t)B_ * N_ * KNN_;
    float* pooled = ws + off; off += (size_t)B_ * J_ * 451;
    float* joints = ws + off; off += (size_t)B_ * J_ * 448;
    float* h1 = ws + off; off += (size_t)B_ * J_ * 512;
    float* h2 = ws + off; off += (size_t)B_ * J_ * 256;
    float* P1 = ws + off; off += szP1;
    float* P2 = ws + off; off += szP2;
    float* P3 = ws + off; off += szP3;
    float* P4 = ws + off; off += szP4;
    float* P5 = ws + off; off += szP5;
    float* P6 = ws + off; off += szP6;
    float* P7 = ws + off; off += szP7;
    float* P8 = ws + off; off += szP8;
    float* P9 = ws + off; off += szP9;
    float* bb1 = ws + off; off += 128;
    float* bb2 = ws + off; off += 256;
    float* bb3 = ws + off; off += 512;
    float* bb4 = ws + off; off += 512;
    float* bb5 = ws + off; off += 256;
    float* bb6 = ws + off; off += 128;

    const int M = B_ * N_;   // 16384
    const int MJ = B_ * J_;  // 96
    const int NUTRI = NTILE * (NTILE + 1) / 2;   // 528 upper-tri tiles

    // ---- all weight prep in one launch ----
    k_prepall<<<dim3((szP4 + 255) / 256, 9), 256, 0, stream>>>(
        g1w, g1b, g2w, g2b, g3w, g3b, s1w, s1b, s2w, s2b, s3w, s3b,
        m1w, m2w, m3w, P1, P2, P3, P4, P5, P6, P7, P8, P9,
        bb1, bb2, bb3, bb4, bb5, bb6);

    // ======== geoNet layer 1: C=3 -> O=64 (fused dist+select, one wave/row) ========
    k_norm<<<(M + 255) / 256, 256, 0, stream>>>(V, xx, 3);
    k_selC3<<<dim3(N_ / 4, B_), 256, 0, stream>>>(V, xx, knnIdx);
    k_gemm<<<dim3(2, M / 64), 256, 0, stream>>>(V, 3, P1, Y, 128, M, 128, 3, bb1, 0);
    k_gathermax<<<M, 64, KNN_ * sizeof(int), stream>>>(Y, 64, N_, knnIdx, KNN_, l1, 64, 0, xx);

    // ======== layer 2: C=64 -> O=128 ========
    for (int b = 0; b < B_; ++b) {
        k_dist<<<NUTRI, 256, 0, stream>>>(l1 + (size_t)b * N_ * 64, 64, xx + b * N_, D);
        k_sel<<<N_ / 4, 256, 0, stream>>>(D, knnIdx + (size_t)b * N_ * KNN_);
    }
    k_gemm<<<dim3(4, M / 64), 256, 0, stream>>>(l1, 64, P2, Y, 256, M, 256, 64, bb2, 0);
    k_gathermax<<<M, 128, KNN_ * sizeof(int), stream>>>(Y, 128, N_, knnIdx, KNN_, l2, 128, 0, xx);

    // ======== layer 3: C=128 -> O=256 ========
    for (int b = 0; b < B_; ++b) {
        k_dist<<<NUTRI, 256, 0, stream>>>(l2 + (size_t)b * N_ * 128, 128, xx + b * N_, D);
        k_sel<<<N_ / 4, 256, 0, stream>>>(D, knnIdx + (size_t)b * N_ * KNN_);
    }
    k_gemm<<<dim3(8, M / 64), 256, 0, stream>>>(l2, 128, P3, Y, 512, M, 512, 128, bb3, 0);
    k_gathermax<<<M, 256, KNN_ * sizeof(int), stream>>>(Y, 256, N_, knnIdx, KNN_, l3, 256, 0, nullptr);

    // ======== pooling onto joints ========
    k_pool2<<<B_ * NSLAB, 256, 0, stream>>>(V, l1, l2, l3, W, ppool, psw);
    k_poolred<<<MJ, 256, 0, stream>>>(ppool, psw, pooled);

    // ======== skeleton convs ========
    k_sgemm<<<dim3(MJ, 2), 256, 451 * sizeof(float), stream>>>(pooled, 451, P4, Y, 512, 512, 451, bb4, 0);
    k_gathermax<<<MJ, 256, KR_ * sizeof(int), stream>>>(Y, 256, J_, ringIdx, KR_, joints, 448, 0, nullptr);

    k_sgemm<<<dim3(MJ, 1), 256, 256 * sizeof(float), stream>>>(joints, 448, P5, Y, 256, 256, 256, bb5, 0);
    k_gathermax<<<MJ, 128, KR_ * sizeof(int), stream>>>(Y, 128, J_, ringIdx, KR_, joints, 448, 256, nullptr);

    k_sgemm<<<dim3(MJ, 1), 256, 128 * sizeof(float), stream>>>(joints + 256, 448, P6, Y, 128, 128, 128, bb6, 0);
    k_gathermax<<<MJ, 64, KR_ * sizeof(int), stream>>>(Y, 64, J_, ringIdx, KR_, joints, 448, 384, nullptr);

    // ======== joint MLP ========
    k_sgemm<<<dim3(MJ, 2), 256, 448 * sizeof(float), stream>>>(joints, 448, P7, h1, 512, 512, 448, m1b, 1);
    k_sgemm<<<dim3(MJ, 1), 256, 512 * sizeof(float), stream>>>(h1, 512, P8, h2, 256, 256, 512, m2b, 1);
    k_sgemm<<<dim3(MJ, 1), 256, 256 * sizeof(float), stream>>>(h2, 256, P9, (float*)d_out, 3, 3, 256, m3b, 0);
}

// Round 14
// 1995.899 us; speedup vs baseline: 1.2855x; 1.2855x over previous
//
#include <hip/hip_runtime.h>
#include <hip/hip_bf16.h>
#include <float.h>

// Problem constants (from reference setup_inputs)
#define B_   4
#define N_   4096
#define J_   24
#define KR_  4
#define KNN_ 20
#define SLOPE 0.2f
#define SLABN 64             // points per pooling slab
#define NSLAB (N_ / SLABN)   // 64
#define NTILE 32             // 128-wide tiles per dim

// ---------- per-point squared norm ----------
__global__ void k_norm(const float* __restrict__ h, float* __restrict__ xx, int C) {
    int i = blockIdx.x * blockDim.x + threadIdx.x;
    if (i >= B_ * N_) return;
    const float* hp = h + (size_t)i * C;
    float s = 0.f;
    for (int c = 0; c < C; ++c) { float v = hp[c]; s += v * v; }
    xx[i] = s;
}

// ---------- symmetric distance GEMM: upper-triangular tiles only ----------
__global__ __launch_bounds__(256) void k_dist(const float* __restrict__ X, int C,
                                              const float* __restrict__ xxb,
                                              float* __restrict__ D) {
    __shared__ float As[16][132];
    __shared__ float Bs[16][132];
    int t = blockIdx.x;                      // linear upper-tri tile id
    int ti = 0;
    while (t >= NTILE - ti) { t -= NTILE - ti; ++ti; }
    int tj = ti + t;
    int row0 = ti * 128, col0 = tj * 128;
    int tid = threadIdx.x;
    int tr = tid >> 4, tc = tid & 15;
    float acc[8][8] = {{0.f}};
    for (int kt = 0; kt < C; kt += 16) {
#pragma unroll
        for (int i = 0; i < 8; ++i) {
            int e = tid + 256 * i;
            int r = e >> 4, kk = e & 15;
            int gk = kt + kk;
            As[kk][r] = (gk < C) ? X[(size_t)(row0 + r) * C + gk] : 0.f;
            Bs[kk][r] = (gk < C) ? X[(size_t)(col0 + r) * C + gk] : 0.f;
        }
        __syncthreads();
#pragma unroll
        for (int kk = 0; kk < 16; ++kk) {
            float a[8], bv[8];
            *(float4*)&a[0]  = *(const float4*)&As[kk][tr * 4];
            *(float4*)&a[4]  = *(const float4*)&As[kk][64 + tr * 4];
            *(float4*)&bv[0] = *(const float4*)&Bs[kk][tc * 4];
            *(float4*)&bv[4] = *(const float4*)&Bs[kk][64 + tc * 4];
#pragma unroll
            for (int i = 0; i < 8; ++i)
#pragma unroll
                for (int j = 0; j < 8; ++j) acc[i][j] += a[i] * bv[j];
        }
        __syncthreads();
    }
    float xc[8], xr[8];
#pragma unroll
    for (int j = 0; j < 4; ++j) {
        xc[j]     = xxb[col0 + tc * 4 + j];
        xc[4 + j] = xxb[col0 + 64 + tc * 4 + j];
        xr[j]     = xxb[row0 + tr * 4 + j];
        xr[4 + j] = xxb[row0 + 64 + tr * 4 + j];
    }
#pragma unroll
    for (int i = 0; i < 8; ++i) {
        int lr = (i < 4) ? (tr * 4 + i) : (64 + tr * 4 + (i - 4));
        float xri = xr[i];
        float4 o0, o1;
        o0.x = xri + xc[0] - 2.f * acc[i][0];
        o0.y = xri + xc[1] - 2.f * acc[i][1];
        o0.z = xri + xc[2] - 2.f * acc[i][2];
        o0.w = xri + xc[3] - 2.f * acc[i][3];
        o1.x = xri + xc[4] - 2.f * acc[i][4];
        o1.y = xri + xc[5] - 2.f * acc[i][5];
        o1.z = xri + xc[6] - 2.f * acc[i][6];
        o1.w = xri + xc[7] - 2.f * acc[i][7];
        float* dp = D + (size_t)(row0 + lr) * N_ + col0;
        *(float4*)(dp + tc * 4)      = o0;
        *(float4*)(dp + 64 + tc * 4) = o1;
    }
    if (ti == tj) return;
    // mirrored store via LDS transpose, 4 passes of 32 dt-rows
    float* tb = &As[0][0];
    for (int p = 0; p < 4; ++p) {
        __syncthreads();
        int h = p >> 1;
        int tclo = (p & 1) * 8;
        if (tc >= tclo && tc < tclo + 8) {
#pragma unroll
            for (int jj = 0; jj < 4; ++jj) {
                int j = h * 4 + jj;
                int cl = h * 64 + tc * 4 + jj - 32 * p;   // 0..31
                float xcj = xc[j];
                float4 vlo, vhi;
                vlo.x = xr[0] + xcj - 2.f * acc[0][j];
                vlo.y = xr[1] + xcj - 2.f * acc[1][j];
                vlo.z = xr[2] + xcj - 2.f * acc[2][j];
                vlo.w = xr[3] + xcj - 2.f * acc[3][j];
                vhi.x = xr[4] + xcj - 2.f * acc[4][j];
                vhi.y = xr[5] + xcj - 2.f * acc[5][j];
                vhi.z = xr[6] + xcj - 2.f * acc[6][j];
                vhi.w = xr[7] + xcj - 2.f * acc[7][j];
                *(float4*)&tb[cl * 132 + tr * 4]      = vlo;
                *(float4*)&tb[cl * 132 + 64 + tr * 4] = vhi;
            }
        }
        __syncthreads();
        int rl  = tid >> 3;
        int c16 = (tid & 7) * 16;
#pragma unroll
        for (int q = 0; q < 4; ++q) {
            float4 v = *(const float4*)&tb[rl * 132 + c16 + q * 4];
            *(float4*)(D + (size_t)(col0 + 32 * p + rl) * N_ + row0 + c16 + q * 4) = v;
        }
    }
}

// ---------- key mapping: monotone f32 -> u32 ----------
__device__ __forceinline__ unsigned mapf(float f) {
    unsigned u = __float_as_uint(f);
    return (u & 0x80000000u) ? ~u : (u | 0x80000000u);
}

// ---------- in-lane top-2 maintenance (strict < keeps smallest index first) ----------
__device__ __forceinline__ void top2_upd(unsigned kv, unsigned ki,
                                         unsigned& b0v, unsigned& b0i,
                                         unsigned& b1v, unsigned& b1i) {
    if (kv < b1v) {
        if (kv < b0v) { b1v = b0v; b1i = b0i; b0v = kv; b0i = ki; }
        else          { b1v = kv;  b1i = ki; }
    }
}

// ---------- top-20 selection: one wave per row, row REGISTER-RESIDENT ----------
// 16 independent float4 loads fill kv[64] (unrolled, static indices -> VGPRs);
// scan, pops, and refills all run from registers. Lane owns 64 contiguous
// cols -> ballot's lowest tied lane == smallest index (exact top_k order).
__global__ __launch_bounds__(256) void k_sel(const float* __restrict__ Db,
                                             int* __restrict__ idxout) {
    const unsigned INV = 0xFFFFFFFFu;
    int q    = blockIdx.x * 4 + (threadIdx.x >> 6);
    int lane = threadIdx.x & 63;
    int gbase = lane * 64;
    const float4* seg4 = (const float4*)(Db + (size_t)q * N_ + gbase);

    float4 r[16];
#pragma unroll
    for (int t = 0; t < 16; ++t) r[t] = seg4[t];   // 16 independent loads (ILP)
    unsigned kv[64];
#pragma unroll
    for (int t = 0; t < 16; ++t) {
        kv[4 * t]     = mapf(r[t].x);
        kv[4 * t + 1] = mapf(r[t].y);
        kv[4 * t + 2] = mapf(r[t].z);
        kv[4 * t + 3] = mapf(r[t].w);
    }

    unsigned b0v = INV, b0i = INV, b1v = INV, b1i = INV;
    unsigned long long emask = 0;
#pragma unroll
    for (int t = 0; t < 64; ++t)
        top2_upd(kv[t], (unsigned)(gbase + t), b0v, b0i, b1v, b1i);

    for (int k = 0; k < KNN_; ++k) {
        if (b0i == INV) {                       // rare refill: rescan REGISTERS
            b0v = INV; b1v = INV; b1i = INV;
#pragma unroll
            for (int t = 0; t < 64; ++t) {
                if ((emask >> t) & 1ull) continue;
                top2_upd(kv[t], (unsigned)(gbase + t), b0v, b0i, b1v, b1i);
            }
        }
        unsigned vm = b0v;
#pragma unroll
        for (int s = 32; s > 0; s >>= 1) {
            unsigned o = (unsigned)__shfl_xor((int)vm, s, 64);
            vm = (o < vm) ? o : vm;
        }
        unsigned long long ball = __ballot(b0v == vm);
        int owner = __ffsll((long long)ball) - 1;   // lowest lane = smallest idx
        unsigned im = (unsigned)__shfl((int)b0i, owner, 64);
        if (lane == owner) {
            emask |= 1ull << (b0i & 63u);
            b0v = b1v; b0i = b1i; b1v = INV; b1i = INV;
        }
        if (lane == 0) idxout[q * KNN_ + k] = (int)im;
    }
}

// ---------- layer-1 fused dist+select (C=3): round-12 proven version ----------
__global__ __launch_bounds__(256) void k_selC3(const float* __restrict__ V,
                                               const float* __restrict__ xx,
                                               int* __restrict__ knnIdx) {
    const unsigned long long SENT = ~0ull;
    const unsigned INV = 0xFFFFFFFFu;
    __shared__ unsigned long long qcs[80];
    int b    = blockIdx.y;
    const float* Xb  = V + (size_t)b * N_ * 3;
    const float* xxb = xx + (size_t)b * N_;
    int* idxout = knnIdx + (size_t)b * N_ * KNN_;
    int q    = blockIdx.x;
    int wv   = threadIdx.x >> 6;
    int lane = threadIdx.x & 63;
    int gbase = wv * 1024 + lane * 16;

    float qx = Xb[q * 3], qy = Xb[q * 3 + 1], qz = Xb[q * 3 + 2];
    float xxq = xxb[q];

    float pts[48];
    const float4* src = (const float4*)(Xb + (size_t)gbase * 3);
#pragma unroll
    for (int t = 0; t < 12; ++t) ((float4*)pts)[t] = src[t];
    float xxm[16];
#pragma unroll
    for (int t = 0; t < 16; ++t) xxm[t] = xxb[gbase + t];

    auto distf = [&](int t) -> float {
        float dot = qx * pts[3 * t];
        dot = fmaf(qy, pts[3 * t + 1], dot);
        dot = fmaf(qz, pts[3 * t + 2], dot);
        return xxq + xxm[t] - 2.f * dot;
    };

    unsigned b0v = INV, b0i = INV, b1v = INV, b1i = INV;
    unsigned emask = 0;
#pragma unroll
    for (int t = 0; t < 16; ++t) {
        unsigned kv = mapf(distf(t));
        if (kv < b1v) {
            if (kv < b0v) { b1v = b0v; b1i = b0i; b0v = kv; b0i = (unsigned)(gbase + t); }
            else          { b1v = kv; b1i = (unsigned)(gbase + t); }
        }
    }
    for (int k = 0; k < KNN_; ++k) {
        if (b0i == INV) {
            b1v = INV; b1i = INV;
            for (int t = 0; t < 16; ++t) {
                if ((emask >> t) & 1u) continue;
                unsigned kv = mapf(distf(t));
                if (kv < b1v) {
                    if (kv < b0v) { b1v = b0v; b1i = b0i; b0v = kv; b0i = (unsigned)(gbase + t); }
                    else          { b1v = kv; b1i = (unsigned)(gbase + t); }
                }
            }
        }
        unsigned m = b0v;
#pragma unroll
        for (int s = 32; s > 0; s >>= 1) {
            unsigned o = (unsigned)__shfl_xor((int)m, s, 64);
            m = (o < m) ? o : m;
        }
        unsigned long long ball = __ballot(b0v == m);
        int owner = __ffsll((long long)ball) - 1;
        unsigned idx = (unsigned)__shfl((int)b0i, owner, 64);
        if (lane == owner) {
            emask |= 1u << (b0i & 15u);
            b0v = b1v; b0i = b1i; b1v = INV; b1i = INV;
        }
        if (lane == 0) qcs[wv * KNN_ + k] = ((unsigned long long)m << 32) | idx;
    }
    __syncthreads();
    if (wv == 0) {
        unsigned long long c0 = qcs[lane];
        unsigned long long c1 = (lane < 16) ? qcs[64 + lane] : SENT;
        if (c1 < c0) { unsigned long long t = c0; c0 = c1; c1 = t; }
        for (int k = 0; k < KNN_; ++k) {
            unsigned long long m = c0;
#pragma unroll
            for (int s = 32; s > 0; s >>= 1) {
                unsigned long long o = (unsigned long long)__shfl_xor((long long)m, s, 64);
                if (o < m) m = o;
            }
            if (m == c0) { c0 = c1; c1 = SENT; }
            if (lane == 0) idxout[q * KNN_ + k] = (int)(unsigned)m;
        }
    }
}

// ---------- fused weight prep ----------
__device__ __forceinline__ void prepP_elem(const float* __restrict__ w,
                                           const float* __restrict__ bias,
                                           int C, int O, float* __restrict__ P,
                                           float* __restrict__ b2, int i) {
    int O2 = 2 * O;
    if (i < O2) b2[i] = (i < O) ? 0.f : bias[i - O];
    if (i >= C * O2) return;
    int k = i / O2, col = i % O2;
    float v;
    if (col < O) v = w[(size_t)col * 2 * C + k];
    else { int o = col - O; v = w[(size_t)o * 2 * C + C + k] - w[(size_t)o * 2 * C + k]; }
    P[i] = v;
}
__device__ __forceinline__ void transp_elem(const float* __restrict__ w, int O, int K,
                                            float* __restrict__ wT, int i) {
    if (i >= O * K) return;
    int k = i / O, o = i % O;
    wT[i] = w[(size_t)o * K + k];
}

__global__ void k_prepall(const float* g1w, const float* g1b,
                          const float* g2w, const float* g2b,
                          const float* g3w, const float* g3b,
                          const float* s1w, const float* s1b,
                          const float* s2w, const float* s2b,
                          const float* s3w, const float* s3b,
                          const float* m1w, const float* m2w, const float* m3w,
                          float* P1, float* P2, float* P3, float* P4, float* P5,
                          float* P6, float* P7, float* P8, float* P9,
                          float* bb1, float* bb2, float* bb3,
                          float* bb4, float* bb5, float* bb6) {
    int i = blockIdx.x * 256 + threadIdx.x;
    switch (blockIdx.y) {
        case 0: prepP_elem(g1w, g1b, 3,   64,  P1, bb1, i); break;
        case 1: prepP_elem(g2w, g2b, 64,  128, P2, bb2, i); break;
        case 2: prepP_elem(g3w, g3b, 128, 256, P3, bb3, i); break;
        case 3: prepP_elem(s1w, s1b, 451, 256, P4, bb4, i); break;
        case 4: prepP_elem(s2w, s2b, 256, 128, P5, bb5, i); break;
        case 5: prepP_elem(s3w, s3b, 128, 64,  P6, bb6, i); break;
        case 6: transp_elem(m1w, 512, 448, P7, i); break;
        case 7: transp_elem(m2w, 256, 512, P8, i); break;
        case 8: transp_elem(m3w, 3,   256, P9, i); break;
    }
}

// ---------- tiled f32 GEMM (large M) ----------
__global__ __launch_bounds__(256) void k_gemm(const float* __restrict__ A, int lda,
                                              const float* __restrict__ Bm,
                                              float* __restrict__ Cm, int ldc,
                                              int M, int N, int K,
                                              const float* __restrict__ bias, int leaky) {
    __shared__ float As[16][68];
    __shared__ float Bs[16][68];
    int tid = threadIdx.x;
    int row0 = blockIdx.y * 64, col0 = blockIdx.x * 64;
    int tr = tid >> 4, tc = tid & 15;
    float acc[4][4] = {{0.f}};
    for (int kt = 0; kt < K; kt += 16) {
#pragma unroll
        for (int i = 0; i < 4; ++i) {
            int e = tid + 256 * i;
            int r = e >> 4, kk = e & 15;
            int gr = row0 + r, gk = kt + kk;
            float v = 0.f;
            if (gr < M && gk < K) v = A[(size_t)gr * lda + gk];
            As[kk][r] = v;
        }
#pragma unroll
        for (int i = 0; i < 4; ++i) {
            int e = tid + 256 * i;
            int kk = e >> 6, c = e & 63;
            int gk = kt + kk, gc = col0 + c;
            float v = 0.f;
            if (gk < K && gc < N) v = Bm[(size_t)gk * N + gc];
            Bs[kk][c] = v;
        }
        __syncthreads();
#pragma unroll
        for (int kk = 0; kk < 16; ++kk) {
            float a[4], bv[4];
            *(float4*)&a[0]  = *(const float4*)&As[kk][tr * 4];
            *(float4*)&bv[0] = *(const float4*)&Bs[kk][tc * 4];
#pragma unroll
            for (int i = 0; i < 4; ++i)
#pragma unroll
                for (int j = 0; j < 4; ++j) acc[i][j] += a[i] * bv[j];
        }
        __syncthreads();
    }
#pragma unroll
    for (int i = 0; i < 4; ++i) {
        int r = row0 + tr * 4 + i;
        if (r >= M) continue;
#pragma unroll
        for (int j = 0; j < 4; ++j) {
            int c = col0 + tc * 4 + j;
            if (c >= N) continue;
            float v = acc[i][j];
            if (bias) v += bias[c];
            if (leaky) v = v >= 0.f ? v : SLOPE * v;
            Cm[(size_t)r * ldc + c] = v;
        }
    }
}

// ---------- small-M GEMM ----------
__global__ __launch_bounds__(256) void k_sgemm(const float* __restrict__ A, int lda,
                                               const float* __restrict__ Bm,
                                               float* __restrict__ Cm, int ldc,
                                               int N, int K,
                                               const float* __restrict__ bias, int leaky) {
    extern __shared__ float Arow[];
    int r   = blockIdx.x;
    int c0  = blockIdx.y * 256;
    int tid = threadIdx.x;
    for (int k = tid; k < K; k += 256) Arow[k] = A[(size_t)r * lda + k];
    __syncthreads();
    int c = c0 + tid;
    if (c >= N) return;
    float acc = bias ? bias[c] : 0.f;
    for (int k = 0; k < K; ++k) acc += Arow[k] * Bm[(size_t)k * N + c];
    if (leaky) acc = acc >= 0.f ? acc : SLOPE * acc;
    Cm[(size_t)r * ldc + c] = acc;
}

// ---------- gather-max epilogue (+ optional fused row-norm) ----------
__global__ void k_gathermax(const float* __restrict__ Y, int O, int R,
                            const int* __restrict__ idx, int kc,
                            float* __restrict__ out, int ldo, int ooff,
                            float* __restrict__ xxout) {
    extern __shared__ int sidx[];
    __shared__ float red[256];
    int br = blockIdx.x;
    int b  = br / R;
    int o  = threadIdx.x;
    if (o < kc) sidx[o] = idx[(size_t)br * kc + o];
    __syncthreads();
    int O2 = 2 * O;
    float z = Y[(size_t)br * O2 + O + o];
    float best = -FLT_MAX;
    for (int k = 0; k < kc; ++k) {
        int m = sidx[k];
        best = fmaxf(best, Y[(size_t)(b * R + m) * O2 + o]);
    }
    float r = z + best;
    r = r >= 0.f ? r : SLOPE * r;
    out[(size_t)br * ldo + ooff + o] = r;
    if (xxout) {
        red[o] = r * r;
        __syncthreads();
        for (int s = blockDim.x >> 1; s > 0; s >>= 1) {
            if (o < s) red[o] += red[o + s];
            __syncthreads();
        }
        if (o == 0) xxout[br] = red[0];
    }
}

// ---------- channel map ----------
__device__ __forceinline__ void chan_map(int b, int c,
                                         const float* Vf, const float* l1,
                                         const float* l2, const float* l3,
                                         const float*& p, int& st) {
    if (c < 3)        { st = 3;   p = Vf + (size_t)b * N_ * 3   + c; }
    else if (c < 67)  { st = 64;  p = l1 + (size_t)b * N_ * 64  + (c - 3); }
    else if (c < 195) { st = 128; p = l2 + (size_t)b * N_ * 128 + (c - 67); }
    else              { st = 256; p = l3 + (size_t)b * N_ * 256 + (c - 195); }
}

// ---------- pooling phase 1 ----------
__global__ __launch_bounds__(256) void k_pool2(const float* __restrict__ Vf,
                                               const float* __restrict__ l1,
                                               const float* __restrict__ l2,
                                               const float* __restrict__ l3,
                                               const float* __restrict__ W,
                                               float* __restrict__ ppool,
                                               float* __restrict__ psw) {
    __shared__ float Wl[SLABN][J_];
    int blk  = blockIdx.x;
    int b    = blk / NSLAB, slab = blk % NSLAB;
    int n0   = slab * SLABN;
    int tid  = threadIdx.x;

    for (int e = tid; e < J_ * SLABN; e += 256) {
        int j = e / SLABN, n = e % SLABN;
        Wl[n][j] = W[((size_t)b * J_ + j) * N_ + n0 + n];
    }
    __syncthreads();

    if (tid < J_) {
        float s = 0.f;
        for (int n = 0; n < SLABN; ++n) s += Wl[n][tid];
        psw[(size_t)blk * J_ + tid] = s;
    }

    int c0 = tid, c1 = tid + 256;
    const float *p0, *p1 = nullptr; int s0, s1 = 0;
    chan_map(b, c0, Vf, l1, l2, l3, p0, s0);
    bool has1 = (c1 < 451);
    if (has1) chan_map(b, c1, Vf, l1, l2, l3, p1, s1);

    float acc0[J_], acc1[J_];
#pragma unroll
    for (int j = 0; j < J_; ++j) { acc0[j] = 0.f; acc1[j] = 0.f; }

    for (int n = 0; n < SLABN; ++n) {
        float v0 = p0[(size_t)(n0 + n) * s0];
        float v1 = has1 ? p1[(size_t)(n0 + n) * s1] : 0.f;
        const float* wn = &Wl[n][0];
#pragma unroll
        for (int q = 0; q < J_ / 4; ++q) {
            float4 w4 = *(const float4*)(wn + 4 * q);
            acc0[4*q+0] += w4.x * v0;  acc1[4*q+0] += w4.x * v1;
            acc0[4*q+1] += w4.y * v0;  acc1[4*q+1] += w4.y * v1;
            acc0[4*q+2] += w4.z * v0;  acc1[4*q+2] += w4.z * v1;
            acc0[4*q+3] += w4.w * v0;  acc1[4*q+3] += w4.w * v1;
        }
    }
    float* pp = ppool + (size_t)blk * J_ * 451;
#pragma unroll
    for (int j = 0; j < J_; ++j) {
        pp[(size_t)j * 451 + c0] = acc0[j];
        if (has1) pp[(size_t)j * 451 + c1] = acc1[j];
    }
}

// ---------- pooling phase 2 ----------
__global__ __launch_bounds__(256) void k_poolred(const float* __restrict__ ppool,
                                                 const float* __restrict__ psw,
                                                 float* __restrict__ pooled) {
    int bj = blockIdx.x;
    int b  = bj / J_, j = bj % J_;
    int tid = threadIdx.x;

    float sw = 0.f;
    for (int sl = 0; sl < NSLAB; ++sl) sw += psw[(size_t)(b * NSLAB + sl) * J_ + j];
    float inv = 1.f / (sw + 1e-5f);

    for (int c = tid; c < 451; c += 256) {
        float s = 0.f;
        for (int sl = 0; sl < NSLAB; ++sl)
            s += ppool[((size_t)(b * NSLAB + sl) * J_ + j) * 451 + c];
        pooled[(size_t)bj * 451 + c] = s * inv;
    }
}

extern "C" void kernel_launch(void* const* d_in, const int* in_sizes, int n_in,
                              void* d_out, int out_size, void* d_ws, size_t ws_size,
                              hipStream_t stream) {
    const float* V  = (const float*)d_in[0];
    const float* W  = (const float*)d_in[1];
    const int* ringIdx = (const int*)d_in[2];
    const float* g1w = (const float*)d_in[3];
    const float* g1b = (const float*)d_in[4];
    const float* g2w = (const float*)d_in[5];
    const float* g2b = (const float*)d_in[6];
    const float* g3w = (const float*)d_in[7];
    const float* g3b = (const float*)d_in[8];
    const float* s1w = (const float*)d_in[9];
    const float* s1b = (const float*)d_in[10];
    const float* s2w = (const float*)d_in[11];
    const float* s2b = (const float*)d_in[12];
    const float* s3w = (const float*)d_in[13];
    const float* s3b = (const float*)d_in[14];
    const float* m1w = (const float*)d_in[15];
    const float* m1b = (const float*)d_in[16];
    const float* m2w = (const float*)d_in[17];
    const float* m2b = (const float*)d_in[18];
    const float* m3w = (const float*)d_in[19];
    const float* m3b = (const float*)d_in[20];
    (void)n_in; (void)in_sizes; (void)out_size; (void)ws_size;

    const int szP1 = 3 * 128,    szP2 = 64 * 256,  szP3 = 128 * 512;
    const int szP4 = 451 * 512,  szP5 = 256 * 256, szP6 = 128 * 128;
    const int szP7 = 448 * 512,  szP8 = 512 * 256, szP9 = 256 * 3;

    // ---- workspace layout (floats); D = full N x N (64 MB, proven fit) ----
    float* ws = (float*)d_ws;
    size_t off = 0;
    float* l1 = ws + off; off += (size_t)B_ * N_ * 64;
    float* l2 = ws + off; off += (size_t)B_ * N_ * 128;
    float* l3 = ws + off; off += (size_t)B_ * N_ * 256;
    float* xx = ws + off; off += (size_t)B_ * N_;
    float* D  = ws + off; off += (size_t)N_ * N_;
    float* Y  = D;
    float* ppool = D;
    float* psw   = D + (size_t)B_ * NSLAB * J_ * 451;
    int* knnIdx = (int*)(ws + off); off += (size_t)B_ * N_ * KNN_;
    float* pooled = ws + off; off += (size_t)B_ * J_ * 451;
    float* joints = ws + off; off += (size_t)B_ * J_ * 448;
    float* h1 = ws + off; off += (size_t)B_ * J_ * 512;
    float* h2 = ws + off; off += (size_t)B_ * J_ * 256;
    float* P1 = ws + off; off += szP1;
    float* P2 = ws + off; off += szP2;
    float* P3 = ws + off; off += szP3;
    float* P4 = ws + off; off += szP4;
    float* P5 = ws + off; off += szP5;
    float* P6 = ws + off; off += szP6;
    float* P7 = ws + off; off += szP7;
    float* P8 = ws + off; off += szP8;
    float* P9 = ws + off; off += szP9;
    float* bb1 = ws + off; off += 128;
    float* bb2 = ws + off; off += 256;
    float* bb3 = ws + off; off += 512;
    float* bb4 = ws + off; off += 512;
    float* bb5 = ws + off; off += 256;
    float* bb6 = ws + off; off += 128;

    const int M = B_ * N_;   // 16384
    const int MJ = B_ * J_;  // 96
    const int NUTRI = NTILE * (NTILE + 1) / 2;   // 528 upper-tri tiles

    // ---- all weight prep in one launch ----
    k_prepall<<<dim3((szP4 + 255) / 256, 9), 256, 0, stream>>>(
        g1w, g1b, g2w, g2b, g3w, g3b, s1w, s1b, s2w, s2b, s3w, s3b,
        m1w, m2w, m3w, P1, P2, P3, P4, P5, P6, P7, P8, P9,
        bb1, bb2, bb3, bb4, bb5, bb6);

    // ======== geoNet layer 1: C=3 -> O=64 (fused dist+select) ========
    k_norm<<<(M + 255) / 256, 256, 0, stream>>>(V, xx, 3);
    k_selC3<<<dim3(N_, B_), 256, 0, stream>>>(V, xx, knnIdx);
    k_gemm<<<dim3(2, M / 64), 256, 0, stream>>>(V, 3, P1, Y, 128, M, 128, 3, bb1, 0);
    k_gathermax<<<M, 64, KNN_ * sizeof(int), stream>>>(Y, 64, N_, knnIdx, KNN_, l1, 64, 0, xx);

    // ======== layer 2: C=64 -> O=128 ========
    for (int b = 0; b < B_; ++b) {
        k_dist<<<NUTRI, 256, 0, stream>>>(l1 + (size_t)b * N_ * 64, 64, xx + b * N_, D);
        k_sel<<<N_ / 4, 256, 0, stream>>>(D, knnIdx + (size_t)b * N_ * KNN_);
    }
    k_gemm<<<dim3(4, M / 64), 256, 0, stream>>>(l1, 64, P2, Y, 256, M, 256, 64, bb2, 0);
    k_gathermax<<<M, 128, KNN_ * sizeof(int), stream>>>(Y, 128, N_, knnIdx, KNN_, l2, 128, 0, xx);

    // ======== layer 3: C=128 -> O=256 ========
    for (int b = 0; b < B_; ++b) {
        k_dist<<<NUTRI, 256, 0, stream>>>(l2 + (size_t)b * N_ * 128, 128, xx + b * N_, D);
        k_sel<<<N_ / 4, 256, 0, stream>>>(D, knnIdx + (size_t)b * N_ * KNN_);
    }
    k_gemm<<<dim3(8, M / 64), 256, 0, stream>>>(l2, 128, P3, Y, 512, M, 512, 128, bb3, 0);
    k_gathermax<<<M, 256, KNN_ * sizeof(int), stream>>>(Y, 256, N_, knnIdx, KNN_, l3, 256, 0, nullptr);

    // ======== pooling onto joints ========
    k_pool2<<<B_ * NSLAB, 256, 0, stream>>>(V, l1, l2, l3, W, ppool, psw);
    k_poolred<<<MJ, 256, 0, stream>>>(ppool, psw, pooled);

    // ======== skeleton convs ========
    k_sgemm<<<dim3(MJ, 2), 256, 451 * sizeof(float), stream>>>(pooled, 451, P4, Y, 512, 512, 451, bb4, 0);
    k_gathermax<<<MJ, 256, KR_ * sizeof(int), stream>>>(Y, 256, J_, ringIdx, KR_, joints, 448, 0, nullptr);

    k_sgemm<<<dim3(MJ, 1), 256, 256 * sizeof(float), stream>>>(joints, 448, P5, Y, 256, 256, 256, bb5, 0);
    k_gathermax<<<MJ, 128, KR_ * sizeof(int), stream>>>(Y, 128, J_, ringIdx, KR_, joints, 448, 256, nullptr);

    k_sgemm<<<dim3(MJ, 1), 256, 128 * sizeof(float), stream>>>(joints + 256, 448, P6, Y, 128, 128, 128, bb6, 0);
    k_gathermax<<<MJ, 64, KR_ * sizeof(int), stream>>>(Y, 64, J_, ringIdx, KR_, joints, 448, 384, nullptr);

    // ======== joint MLP ========
    k_sgemm<<<dim3(MJ, 2), 256, 448 * sizeof(float), stream>>>(joints, 448, P7, h1, 512, 512, 448, m1b, 1);
    k_sgemm<<<dim3(MJ, 1), 256, 512 * sizeof(float), stream>>>(h1, 512, P8, h2, 256, 256, 512, m2b, 1);
    k_sgemm<<<dim3(MJ, 1), 256, 256 * sizeof(float), stream>>>(h2, 256, P9, (float*)d_out, 3, 3, 256, m3b, 0);
}

// Round 15
// 1467.789 us; speedup vs baseline: 1.7480x; 1.3598x over previous
//
#include <hip/hip_runtime.h>
#include <hip/hip_bf16.h>
#include <float.h>

// Problem constants (from reference setup_inputs)
#define B_   4
#define N_   4096
#define J_   24
#define KR_  4
#define KNN_ 20
#define SLOPE 0.2f
#define SLABN 64             // points per pooling slab
#define NSLAB (N_ / SLABN)   // 64
#define NTILE 32             // 128-wide tiles per dim

// ---------- per-point squared norm ----------
__global__ void k_norm(const float* __restrict__ h, float* __restrict__ xx, int C) {
    int i = blockIdx.x * blockDim.x + threadIdx.x;
    if (i >= B_ * N_) return;
    const float* hp = h + (size_t)i * C;
    float s = 0.f;
    for (int c = 0; c < C; ++c) { float v = hp[c]; s += v * v; }
    xx[i] = s;
}

// ---------- symmetric distance GEMM: upper-triangular tiles only ----------
__global__ __launch_bounds__(256) void k_dist(const float* __restrict__ X, int C,
                                              const float* __restrict__ xxb,
                                              float* __restrict__ D) {
    __shared__ float As[16][132];
    __shared__ float Bs[16][132];
    int t = blockIdx.x;                      // linear upper-tri tile id
    int ti = 0;
    while (t >= NTILE - ti) { t -= NTILE - ti; ++ti; }
    int tj = ti + t;
    int row0 = ti * 128, col0 = tj * 128;
    int tid = threadIdx.x;
    int tr = tid >> 4, tc = tid & 15;
    float acc[8][8] = {{0.f}};
    for (int kt = 0; kt < C; kt += 16) {
#pragma unroll
        for (int i = 0; i < 8; ++i) {
            int e = tid + 256 * i;
            int r = e >> 4, kk = e & 15;
            int gk = kt + kk;
            As[kk][r] = (gk < C) ? X[(size_t)(row0 + r) * C + gk] : 0.f;
            Bs[kk][r] = (gk < C) ? X[(size_t)(col0 + r) * C + gk] : 0.f;
        }
        __syncthreads();
#pragma unroll
        for (int kk = 0; kk < 16; ++kk) {
            float a[8], bv[8];
            *(float4*)&a[0]  = *(const float4*)&As[kk][tr * 4];
            *(float4*)&a[4]  = *(const float4*)&As[kk][64 + tr * 4];
            *(float4*)&bv[0] = *(const float4*)&Bs[kk][tc * 4];
            *(float4*)&bv[4] = *(const float4*)&Bs[kk][64 + tc * 4];
#pragma unroll
            for (int i = 0; i < 8; ++i)
#pragma unroll
                for (int j = 0; j < 8; ++j) acc[i][j] += a[i] * bv[j];
        }
        __syncthreads();
    }
    float xc[8], xr[8];
#pragma unroll
    for (int j = 0; j < 4; ++j) {
        xc[j]     = xxb[col0 + tc * 4 + j];
        xc[4 + j] = xxb[col0 + 64 + tc * 4 + j];
        xr[j]     = xxb[row0 + tr * 4 + j];
        xr[4 + j] = xxb[row0 + 64 + tr * 4 + j];
    }
#pragma unroll
    for (int i = 0; i < 8; ++i) {
        int lr = (i < 4) ? (tr * 4 + i) : (64 + tr * 4 + (i - 4));
        float xri = xr[i];
        float4 o0, o1;
        o0.x = xri + xc[0] - 2.f * acc[i][0];
        o0.y = xri + xc[1] - 2.f * acc[i][1];
        o0.z = xri + xc[2] - 2.f * acc[i][2];
        o0.w = xri + xc[3] - 2.f * acc[i][3];
        o1.x = xri + xc[4] - 2.f * acc[i][4];
        o1.y = xri + xc[5] - 2.f * acc[i][5];
        o1.z = xri + xc[6] - 2.f * acc[i][6];
        o1.w = xri + xc[7] - 2.f * acc[i][7];
        float* dp = D + (size_t)(row0 + lr) * N_ + col0;
        *(float4*)(dp + tc * 4)      = o0;
        *(float4*)(dp + 64 + tc * 4) = o1;
    }
    if (ti == tj) return;
    // mirrored store via LDS transpose, 4 passes of 32 dt-rows
    float* tb = &As[0][0];
    for (int p = 0; p < 4; ++p) {
        __syncthreads();
        int h = p >> 1;
        int tclo = (p & 1) * 8;
        if (tc >= tclo && tc < tclo + 8) {
#pragma unroll
            for (int jj = 0; jj < 4; ++jj) {
                int j = h * 4 + jj;
                int cl = h * 64 + tc * 4 + jj - 32 * p;   // 0..31
                float xcj = xc[j];
                float4 vlo, vhi;
                vlo.x = xr[0] + xcj - 2.f * acc[0][j];
                vlo.y = xr[1] + xcj - 2.f * acc[1][j];
                vlo.z = xr[2] + xcj - 2.f * acc[2][j];
                vlo.w = xr[3] + xcj - 2.f * acc[3][j];
                vhi.x = xr[4] + xcj - 2.f * acc[4][j];
                vhi.y = xr[5] + xcj - 2.f * acc[5][j];
                vhi.z = xr[6] + xcj - 2.f * acc[6][j];
                vhi.w = xr[7] + xcj - 2.f * acc[7][j];
                *(float4*)&tb[cl * 132 + tr * 4]      = vlo;
                *(float4*)&tb[cl * 132 + 64 + tr * 4] = vhi;
            }
        }
        __syncthreads();
        int rl  = tid >> 3;
        int c16 = (tid & 7) * 16;
#pragma unroll
        for (int q = 0; q < 4; ++q) {
            float4 v = *(const float4*)&tb[rl * 132 + c16 + q * 4];
            *(float4*)(D + (size_t)(col0 + 32 * p + rl) * N_ + row0 + c16 + q * 4) = v;
        }
    }
}

// ---------- key mapping: monotone f32 -> u32 ----------
__device__ __forceinline__ unsigned mapf(float f) {
    unsigned u = __float_as_uint(f);
    return (u & 0x80000000u) ? ~u : (u | 0x80000000u);
}

// ---------- fused top-20 selection over materialized D (4 quarters + merge) ----------
__global__ __launch_bounds__(256) void k_sel(const float* __restrict__ Db,
                                             int* __restrict__ idxout) {
    const unsigned long long SENT = ~0ull;
    const unsigned INV = 0xFFFFFFFFu;
    __shared__ unsigned long long qcs[80];
    int ql   = blockIdx.x;
    int wv   = threadIdx.x >> 6;
    int lane = threadIdx.x & 63;
    int gbase = wv * 1024 + lane * 16;
    const float* seg = Db + (size_t)ql * N_ + gbase;

    float4 v4[4];
    v4[0] = *(const float4*)(seg);
    v4[1] = *(const float4*)(seg + 4);
    v4[2] = *(const float4*)(seg + 8);
    v4[3] = *(const float4*)(seg + 12);
    const float* vv = (const float*)v4;

    unsigned b0v = INV, b0i = INV, b1v = INV, b1i = INV;
    unsigned emask = 0;
#pragma unroll
    for (int t = 0; t < 16; ++t) {
        unsigned kv = mapf(vv[t]);
        if (kv < b1v) {
            if (kv < b0v) { b1v = b0v; b1i = b0i; b0v = kv; b0i = (unsigned)(gbase + t); }
            else          { b1v = kv; b1i = (unsigned)(gbase + t); }
        }
    }
    for (int k = 0; k < KNN_; ++k) {
        if (b0i == INV) {
            b1v = INV; b1i = INV;
            for (int t = 0; t < 16; ++t) {
                if ((emask >> t) & 1u) continue;
                unsigned kv = mapf(seg[t]);
                if (kv < b1v) {
                    if (kv < b0v) { b1v = b0v; b1i = b0i; b0v = kv; b0i = (unsigned)(gbase + t); }
                    else          { b1v = kv; b1i = (unsigned)(gbase + t); }
                }
            }
        }
        unsigned m = b0v;
#pragma unroll
        for (int s = 32; s > 0; s >>= 1) {
            unsigned o = (unsigned)__shfl_xor((int)m, s, 64);
            m = (o < m) ? o : m;
        }
        unsigned long long ball = __ballot(b0v == m);
        int owner = __ffsll((long long)ball) - 1;
        unsigned idx = (unsigned)__shfl((int)b0i, owner, 64);
        if (lane == owner) {
            emask |= 1u << (b0i & 15u);
            b0v = b1v; b0i = b1i; b1v = INV; b1i = INV;
        }
        if (lane == 0) qcs[wv * KNN_ + k] = ((unsigned long long)m << 32) | idx;
    }
    __syncthreads();
    if (wv == 0) {
        unsigned long long c0 = qcs[lane];
        unsigned long long c1 = (lane < 16) ? qcs[64 + lane] : SENT;
        if (c1 < c0) { unsigned long long t = c0; c0 = c1; c1 = t; }
        for (int k = 0; k < KNN_; ++k) {
            unsigned long long m = c0;
#pragma unroll
            for (int s = 32; s > 0; s >>= 1) {
                unsigned long long o = (unsigned long long)__shfl_xor((long long)m, s, 64);
                if (o < m) m = o;
            }
            if (m == c0) { c0 = c1; c1 = SENT; }
            if (lane == 0) idxout[ql * KNN_ + k] = (int)(unsigned)m;
        }
    }
}

// ---------- layer-1 fused dist+select (C=3), all batches in one launch ----------
__global__ __launch_bounds__(256) void k_selC3(const float* __restrict__ V,
                                               const float* __restrict__ xx,
                                               int* __restrict__ knnIdx) {
    const unsigned long long SENT = ~0ull;
    const unsigned INV = 0xFFFFFFFFu;
    __shared__ unsigned long long qcs[80];
    int b    = blockIdx.y;
    const float* Xb  = V + (size_t)b * N_ * 3;
    const float* xxb = xx + (size_t)b * N_;
    int* idxout = knnIdx + (size_t)b * N_ * KNN_;
    int q    = blockIdx.x;
    int wv   = threadIdx.x >> 6;
    int lane = threadIdx.x & 63;
    int gbase = wv * 1024 + lane * 16;

    float qx = Xb[q * 3], qy = Xb[q * 3 + 1], qz = Xb[q * 3 + 2];
    float xxq = xxb[q];

    float pts[48];
    const float4* src = (const float4*)(Xb + (size_t)gbase * 3);
#pragma unroll
    for (int t = 0; t < 12; ++t) ((float4*)pts)[t] = src[t];
    float xxm[16];
#pragma unroll
    for (int t = 0; t < 16; ++t) xxm[t] = xxb[gbase + t];

    auto distf = [&](int t) -> float {
        float dot = qx * pts[3 * t];
        dot = fmaf(qy, pts[3 * t + 1], dot);
        dot = fmaf(qz, pts[3 * t + 2], dot);
        return xxq + xxm[t] - 2.f * dot;
    };

    unsigned b0v = INV, b0i = INV, b1v = INV, b1i = INV;
    unsigned emask = 0;
#pragma unroll
    for (int t = 0; t < 16; ++t) {
        unsigned kv = mapf(distf(t));
        if (kv < b1v) {
            if (kv < b0v) { b1v = b0v; b1i = b0i; b0v = kv; b0i = (unsigned)(gbase + t); }
            else          { b1v = kv; b1i = (unsigned)(gbase + t); }
        }
    }
    for (int k = 0; k < KNN_; ++k) {
        if (b0i == INV) {
            b1v = INV; b1i = INV;
            for (int t = 0; t < 16; ++t) {
                if ((emask >> t) & 1u) continue;
                unsigned kv = mapf(distf(t));
                if (kv < b1v) {
                    if (kv < b0v) { b1v = b0v; b1i = b0i; b0v = kv; b0i = (unsigned)(gbase + t); }
                    else          { b1v = kv; b1i = (unsigned)(gbase + t); }
                }
            }
        }
        unsigned m = b0v;
#pragma unroll
        for (int s = 32; s > 0; s >>= 1) {
            unsigned o = (unsigned)__shfl_xor((int)m, s, 64);
            m = (o < m) ? o : m;
        }
        unsigned long long ball = __ballot(b0v == m);
        int owner = __ffsll((long long)ball) - 1;
        unsigned idx = (unsigned)__shfl((int)b0i, owner, 64);
        if (lane == owner) {
            emask |= 1u << (b0i & 15u);
            b0v = b1v; b0i = b1i; b1v = INV; b1i = INV;
        }
        if (lane == 0) qcs[wv * KNN_ + k] = ((unsigned long long)m << 32) | idx;
    }
    __syncthreads();
    if (wv == 0) {
        unsigned long long c0 = qcs[lane];
        unsigned long long c1 = (lane < 16) ? qcs[64 + lane] : SENT;
        if (c1 < c0) { unsigned long long t = c0; c0 = c1; c1 = t; }
        for (int k = 0; k < KNN_; ++k) {
            unsigned long long m = c0;
#pragma unroll
            for (int s = 32; s > 0; s >>= 1) {
                unsigned long long o = (unsigned long long)__shfl_xor((long long)m, s, 64);
                if (o < m) m = o;
            }
            if (m == c0) { c0 = c1; c1 = SENT; }
            if (lane == 0) idxout[q * KNN_ + k] = (int)(unsigned)m;
        }
    }
}

// ---------- fused weight prep ----------
__device__ __forceinline__ void prepP_elem(const float* __restrict__ w,
                                           const float* __restrict__ bias,
                                           int C, int O, float* __restrict__ P,
                                           float* __restrict__ b2, int i) {
    int O2 = 2 * O;
    if (i < O2) b2[i] = (i < O) ? 0.f : bias[i - O];
    if (i >= C * O2) return;
    int k = i / O2, col = i % O2;
    float v;
    if (col < O) v = w[(size_t)col * 2 * C + k];
    else { int o = col - O; v = w[(size_t)o * 2 * C + C + k] - w[(size_t)o * 2 * C + k]; }
    P[i] = v;
}
__device__ __forceinline__ void transp_elem(const float* __restrict__ w, int O, int K,
                                            float* __restrict__ wT, int i) {
    if (i >= O * K) return;
    int k = i / O, o = i % O;
    wT[i] = w[(size_t)o * K + k];
}

__global__ void k_prepall(const float* g1w, const float* g1b,
                          const float* g2w, const float* g2b,
                          const float* g3w, const float* g3b,
                          const float* s1w, const float* s1b,
                          const float* s2w, const float* s2b,
                          const float* s3w, const float* s3b,
                          const float* m1w, const float* m2w, const float* m3w,
                          float* P1, float* P2, float* P3, float* P4, float* P5,
                          float* P6, float* P7, float* P8, float* P9,
                          float* bb1, float* bb2, float* bb3,
                          float* bb4, float* bb5, float* bb6) {
    int i = blockIdx.x * 256 + threadIdx.x;
    switch (blockIdx.y) {
        case 0: prepP_elem(g1w, g1b, 3,   64,  P1, bb1, i); break;
        case 1: prepP_elem(g2w, g2b, 64,  128, P2, bb2, i); break;
        case 2: prepP_elem(g3w, g3b, 128, 256, P3, bb3, i); break;
        case 3: prepP_elem(s1w, s1b, 451, 256, P4, bb4, i); break;
        case 4: prepP_elem(s2w, s2b, 256, 128, P5, bb5, i); break;
        case 5: prepP_elem(s3w, s3b, 128, 64,  P6, bb6, i); break;
        case 6: transp_elem(m1w, 512, 448, P7, i); break;
        case 7: transp_elem(m2w, 256, 512, P8, i); break;
        case 8: transp_elem(m3w, 3,   256, P9, i); break;
    }
}

// ---------- tiled f32 GEMM (large M) ----------
__global__ __launch_bounds__(256) void k_gemm(const float* __restrict__ A, int lda,
                                              const float* __restrict__ Bm,
                                              float* __restrict__ Cm, int ldc,
                                              int M, int N, int K,
                                              const float* __restrict__ bias, int leaky) {
    __shared__ float As[16][68];
    __shared__ float Bs[16][68];
    int tid = threadIdx.x;
    int row0 = blockIdx.y * 64, col0 = blockIdx.x * 64;
    int tr = tid >> 4, tc = tid & 15;
    float acc[4][4] = {{0.f}};
    for (int kt = 0; kt < K; kt += 16) {
#pragma unroll
        for (int i = 0; i < 4; ++i) {
            int e = tid + 256 * i;
            int r = e >> 4, kk = e & 15;
            int gr = row0 + r, gk = kt + kk;
            float v = 0.f;
            if (gr < M && gk < K) v = A[(size_t)gr * lda + gk];
            As[kk][r] = v;
        }
#pragma unroll
        for (int i = 0; i < 4; ++i) {
            int e = tid + 256 * i;
            int kk = e >> 6, c = e & 63;
            int gk = kt + kk, gc = col0 + c;
            float v = 0.f;
            if (gk < K && gc < N) v = Bm[(size_t)gk * N + gc];
            Bs[kk][c] = v;
        }
        __syncthreads();
#pragma unroll
        for (int kk = 0; kk < 16; ++kk) {
            float a[4], bv[4];
            *(float4*)&a[0]  = *(const float4*)&As[kk][tr * 4];
            *(float4*)&bv[0] = *(const float4*)&Bs[kk][tc * 4];
#pragma unroll
            for (int i = 0; i < 4; ++i)
#pragma unroll
                for (int j = 0; j < 4; ++j) acc[i][j] += a[i] * bv[j];
        }
        __syncthreads();
    }
#pragma unroll
    for (int i = 0; i < 4; ++i) {
        int r = row0 + tr * 4 + i;
        if (r >= M) continue;
#pragma unroll
        for (int j = 0; j < 4; ++j) {
            int c = col0 + tc * 4 + j;
            if (c >= N) continue;
            float v = acc[i][j];
            if (bias) v += bias[c];
            if (leaky) v = v >= 0.f ? v : SLOPE * v;
            Cm[(size_t)r * ldc + c] = v;
        }
    }
}

// ---------- small-M GEMM ----------
__global__ __launch_bounds__(256) void k_sgemm(const float* __restrict__ A, int lda,
                                               const float* __restrict__ Bm,
                                               float* __restrict__ Cm, int ldc,
                                               int N, int K,
                                               const float* __restrict__ bias, int leaky) {
    extern __shared__ float Arow[];
    int r   = blockIdx.x;
    int c0  = blockIdx.y * 256;
    int tid = threadIdx.x;
    for (int k = tid; k < K; k += 256) Arow[k] = A[(size_t)r * lda + k];
    __syncthreads();
    int c = c0 + tid;
    if (c >= N) return;
    float acc = bias ? bias[c] : 0.f;
    for (int k = 0; k < K; ++k) acc += Arow[k] * Bm[(size_t)k * N + c];
    if (leaky) acc = acc >= 0.f ? acc : SLOPE * acc;
    Cm[(size_t)r * ldc + c] = acc;
}

// ---------- gather-max epilogue (+ optional fused row-norm) ----------
__global__ void k_gathermax(const float* __restrict__ Y, int O, int R,
                            const int* __restrict__ idx, int kc,
                            float* __restrict__ out, int ldo, int ooff,
                            float* __restrict__ xxout) {
    extern __shared__ int sidx[];
    __shared__ float red[256];
    int br = blockIdx.x;
    int b  = br / R;
    int o  = threadIdx.x;
    if (o < kc) sidx[o] = idx[(size_t)br * kc + o];
    __syncthreads();
    int O2 = 2 * O;
    float z = Y[(size_t)br * O2 + O + o];
    float best = -FLT_MAX;
    for (int k = 0; k < kc; ++k) {
        int m = sidx[k];
        best = fmaxf(best, Y[(size_t)(b * R + m) * O2 + o]);
    }
    float r = z + best;
    r = r >= 0.f ? r : SLOPE * r;
    out[(size_t)br * ldo + ooff + o] = r;
    if (xxout) {
        red[o] = r * r;
        __syncthreads();
        for (int s = blockDim.x >> 1; s > 0; s >>= 1) {
            if (o < s) red[o] += red[o + s];
            __syncthreads();
        }
        if (o == 0) xxout[br] = red[0];
    }
}

// ---------- channel map ----------
__device__ __forceinline__ void chan_map(int b, int c,
                                         const float* Vf, const float* l1,
                                         const float* l2, const float* l3,
                                         const float*& p, int& st) {
    if (c < 3)        { st = 3;   p = Vf + (size_t)b * N_ * 3   + c; }
    else if (c < 67)  { st = 64;  p = l1 + (size_t)b * N_ * 64  + (c - 3); }
    else if (c < 195) { st = 128; p = l2 + (size_t)b * N_ * 128 + (c - 67); }
    else              { st = 256; p = l3 + (size_t)b * N_ * 256 + (c - 195); }
}

// ---------- pooling phase 1 ----------
__global__ __launch_bounds__(256) void k_pool2(const float* __restrict__ Vf,
                                               const float* __restrict__ l1,
                                               const float* __restrict__ l2,
                                               const float* __restrict__ l3,
                                               const float* __restrict__ W,
                                               float* __restrict__ ppool,
                                               float* __restrict__ psw) {
    __shared__ float Wl[SLABN][J_];
    int blk  = blockIdx.x;
    int b    = blk / NSLAB, slab = blk % NSLAB;
    int n0   = slab * SLABN;
    int tid  = threadIdx.x;

    for (int e = tid; e < J_ * SLABN; e += 256) {
        int j = e / SLABN, n = e % SLABN;
        Wl[n][j] = W[((size_t)b * J_ + j) * N_ + n0 + n];
    }
    __syncthreads();

    if (tid < J_) {
        float s = 0.f;
        for (int n = 0; n < SLABN; ++n) s += Wl[n][tid];
        psw[(size_t)blk * J_ + tid] = s;
    }

    int c0 = tid, c1 = tid + 256;
    const float *p0, *p1 = nullptr; int s0, s1 = 0;
    chan_map(b, c0, Vf, l1, l2, l3, p0, s0);
    bool has1 = (c1 < 451);
    if (has1) chan_map(b, c1, Vf, l1, l2, l3, p1, s1);

    float acc0[J_], acc1[J_];
#pragma unroll
    for (int j = 0; j < J_; ++j) { acc0[j] = 0.f; acc1[j] = 0.f; }

    for (int n = 0; n < SLABN; ++n) {
        float v0 = p0[(size_t)(n0 + n) * s0];
        float v1 = has1 ? p1[(size_t)(n0 + n) * s1] : 0.f;
        const float* wn = &Wl[n][0];
#pragma unroll
        for (int q = 0; q < J_ / 4; ++q) {
            float4 w4 = *(const float4*)(wn + 4 * q);
            acc0[4*q+0] += w4.x * v0;  acc1[4*q+0] += w4.x * v1;
            acc0[4*q+1] += w4.y * v0;  acc1[4*q+1] += w4.y * v1;
            acc0[4*q+2] += w4.z * v0;  acc1[4*q+2] += w4.z * v1;
            acc0[4*q+3] += w4.w * v0;  acc1[4*q+3] += w4.w * v1;
        }
    }
    float* pp = ppool + (size_t)blk * J_ * 451;
#pragma unroll
    for (int j = 0; j < J_; ++j) {
        pp[(size_t)j * 451 + c0] = acc0[j];
        if (has1) pp[(size_t)j * 451 + c1] = acc1[j];
    }
}

// ---------- pooling phase 2 ----------
__global__ __launch_bounds__(256) void k_poolred(const float* __restrict__ ppool,
                                                 const float* __restrict__ psw,
                                                 float* __restrict__ pooled) {
    int bj = blockIdx.x;
    int b  = bj / J_, j = bj % J_;
    int tid = threadIdx.x;

    float sw = 0.f;
    for (int sl = 0; sl < NSLAB; ++sl) sw += psw[(size_t)(b * NSLAB + sl) * J_ + j];
    float inv = 1.f / (sw + 1e-5f);

    for (int c = tid; c < 451; c += 256) {
        float s = 0.f;
        for (int sl = 0; sl < NSLAB; ++sl)
            s += ppool[((size_t)(b * NSLAB + sl) * J_ + j) * 451 + c];
        pooled[(size_t)bj * 451 + c] = s * inv;
    }
}

extern "C" void kernel_launch(void* const* d_in, const int* in_sizes, int n_in,
                              void* d_out, int out_size, void* d_ws, size_t ws_size,
                              hipStream_t stream) {
    const float* V  = (const float*)d_in[0];
    const float* W  = (const float*)d_in[1];
    const int* ringIdx = (const int*)d_in[2];
    const float* g1w = (const float*)d_in[3];
    const float* g1b = (const float*)d_in[4];
    const float* g2w = (const float*)d_in[5];
    const float* g2b = (const float*)d_in[6];
    const float* g3w = (const float*)d_in[7];
    const float* g3b = (const float*)d_in[8];
    const float* s1w = (const float*)d_in[9];
    const float* s1b = (const float*)d_in[10];
    const float* s2w = (const float*)d_in[11];
    const float* s2b = (const float*)d_in[12];
    const float* s3w = (const float*)d_in[13];
    const float* s3b = (const float*)d_in[14];
    const float* m1w = (const float*)d_in[15];
    const float* m1b = (const float*)d_in[16];
    const float* m2w = (const float*)d_in[17];
    const float* m2b = (const float*)d_in[18];
    const float* m3w = (const float*)d_in[19];
    const float* m3b = (const float*)d_in[20];
    (void)n_in; (void)in_sizes; (void)out_size; (void)ws_size;

    const int szP1 = 3 * 128,    szP2 = 64 * 256,  szP3 = 128 * 512;
    const int szP4 = 451 * 512,  szP5 = 256 * 256, szP6 = 128 * 128;
    const int szP7 = 448 * 512,  szP8 = 512 * 256, szP9 = 256 * 3;

    // ---- workspace layout (floats); D = full N x N (64 MB, proven fit) ----
    float* ws = (float*)d_ws;
    size_t off = 0;
    float* l1 = ws + off; off += (size_t)B_ * N_ * 64;
    float* l2 = ws + off; off += (size_t)B_ * N_ * 128;
    float* l3 = ws + off; off += (size_t)B_ * N_ * 256;
    float* xx = ws + off; off += (size_t)B_ * N_;
    float* D  = ws + off; off += (size_t)N_ * N_;
    float* Y  = D;
    float* ppool = D;
    float* psw   = D + (size_t)B_ * NSLAB * J_ * 451;
    int* knnIdx = (int*)(ws + off); off += (size_t)B_ * N_ * KNN_;
    float* pooled = ws + off; off += (size_t)B_ * J_ * 451;
    float* joints = ws + off; off += (size_t)B_ * J_ * 448;
    float* h1 = ws + off; off += (size_t)B_ * J_ * 512;
    float* h2 = ws + off; off += (size_t)B_ * J_ * 256;
    float* P1 = ws + off; off += szP1;
    float* P2 = ws + off; off += szP2;
    float* P3 = ws + off; off += szP3;
    float* P4 = ws + off; off += szP4;
    float* P5 = ws + off; off += szP5;
    float* P6 = ws + off; off += szP6;
    float* P7 = ws + off; off += szP7;
    float* P8 = ws + off; off += szP8;
    float* P9 = ws + off; off += szP9;
    float* bb1 = ws + off; off += 128;
    float* bb2 = ws + off; off += 256;
    float* bb3 = ws + off; off += 512;
    float* bb4 = ws + off; off += 512;
    float* bb5 = ws + off; off += 256;
    float* bb6 = ws + off; off += 128;

    const int M = B_ * N_;   // 16384
    const int MJ = B_ * J_;  // 96
    const int NUTRI = NTILE * (NTILE + 1) / 2;   // 528 upper-tri tiles

    // ---- all weight prep in one launch ----
    k_prepall<<<dim3((szP4 + 255) / 256, 9), 256, 0, stream>>>(
        g1w, g1b, g2w, g2b, g3w, g3b, s1w, s1b, s2w, s2b, s3w, s3b,
        m1w, m2w, m3w, P1, P2, P3, P4, P5, P6, P7, P8, P9,
        bb1, bb2, bb3, bb4, bb5, bb6);

    // ======== geoNet layer 1: C=3 -> O=64 (fused dist+select) ========
    k_norm<<<(M + 255) / 256, 256, 0, stream>>>(V, xx, 3);
    k_selC3<<<dim3(N_, B_), 256, 0, stream>>>(V, xx, knnIdx);
    k_gemm<<<dim3(2, M / 64), 256, 0, stream>>>(V, 3, P1, Y, 128, M, 128, 3, bb1, 0);
    k_gathermax<<<M, 64, KNN_ * sizeof(int), stream>>>(Y, 64, N_, knnIdx, KNN_, l1, 64, 0, xx);

    // ======== layer 2: C=64 -> O=128 ========
    for (int b = 0; b < B_; ++b) {
        k_dist<<<NUTRI, 256, 0, stream>>>(l1 + (size_t)b * N_ * 64, 64, xx + b * N_, D);
        k_sel<<<N_, 256, 0, stream>>>(D, knnIdx + (size_t)b * N_ * KNN_);
    }
    k_gemm<<<dim3(4, M / 64), 256, 0, stream>>>(l1, 64, P2, Y, 256, M, 256, 64, bb2, 0);
    k_gathermax<<<M, 128, KNN_ * sizeof(int), stream>>>(Y, 128, N_, knnIdx, KNN_, l2, 128, 0, xx);

    // ======== layer 3: C=128 -> O=256 ========
    for (int b = 0; b < B_; ++b) {
        k_dist<<<NUTRI, 256, 0, stream>>>(l2 + (size_t)b * N_ * 128, 128, xx + b * N_, D);
        k_sel<<<N_, 256, 0, stream>>>(D, knnIdx + (size_t)b * N_ * KNN_);
    }
    k_gemm<<<dim3(8, M / 64), 256, 0, stream>>>(l2, 128, P3, Y, 512, M, 512, 128, bb3, 0);
    k_gathermax<<<M, 256, KNN_ * sizeof(int), stream>>>(Y, 256, N_, knnIdx, KNN_, l3, 256, 0, nullptr);

    // ======== pooling onto joints ========
    k_pool2<<<B_ * NSLAB, 256, 0, stream>>>(V, l1, l2, l3, W, ppool, psw);
    k_poolred<<<MJ, 256, 0, stream>>>(ppool, psw, pooled);

    // ======== skeleton convs ========
    k_sgemm<<<dim3(MJ, 2), 256, 451 * sizeof(float), stream>>>(pooled, 451, P4, Y, 512, 512, 451, bb4, 0);
    k_gathermax<<<MJ, 256, KR_ * sizeof(int), stream>>>(Y, 256, J_, ringIdx, KR_, joints, 448, 0, nullptr);

    k_sgemm<<<dim3(MJ, 1), 256, 256 * sizeof(float), stream>>>(joints, 448, P5, Y, 256, 256, 256, bb5, 0);
    k_gathermax<<<MJ, 128, KR_ * sizeof(int), stream>>>(Y, 128, J_, ringIdx, KR_, joints, 448, 256, nullptr);

    k_sgemm<<<dim3(MJ, 1), 256, 128 * sizeof(float), stream>>>(joints + 256, 448, P6, Y, 128, 128, 128, bb6, 0);
    k_gathermax<<<MJ, 64, KR_ * sizeof(int), stream>>>(Y, 64, J_, ringIdx, KR_, joints, 448, 384, nullptr);

    // ======== joint MLP ========
    k_sgemm<<<dim3(MJ, 2), 256, 448 * sizeof(float), stream>>>(joints, 448, P7, h1, 512, 512, 448, m1b, 1);
    k_sgemm<<<dim3(MJ, 1), 256, 512 * sizeof(float), stream>>>(h1, 512, P8, h2, 256, 256, 512, m2b, 1);
    k_sgemm<<<dim3(MJ, 1), 256, 256 * sizeof(float), stream>>>(h2, 256, P9, (float*)d_out, 3, 3, 256, m3b, 0);
}

// Round 16
// 1298.299 us; speedup vs baseline: 1.9762x; 1.1305x over previous
//
#include <hip/hip_runtime.h>
#include <hip/hip_bf16.h>
#include <float.h>

// Problem constants (from reference setup_inputs)
#define B_   4
#define N_   4096
#define J_   24
#define KR_  4
#define KNN_ 20
#define SLOPE 0.2f
#define SLABN 64             // points per pooling slab
#define NSLAB (N_ / SLABN)   // 64
#define NTILE 32             // 128-wide tiles per dim

// ---------- per-point squared norm ----------
__global__ void k_norm(const float* __restrict__ h, float* __restrict__ xx, int C) {
    int i = blockIdx.x * blockDim.x + threadIdx.x;
    if (i >= B_ * N_) return;
    const float* hp = h + (size_t)i * C;
    float s = 0.f;
    for (int c = 0; c < C; ++c) { float v = hp[c]; s += v * v; }
    xx[i] = s;
}

// ---------- symmetric distance GEMM: upper-tri tiles; grid.y = batch in group ----------
__global__ __launch_bounds__(256) void k_dist(const float* __restrict__ Xall, int C,
                                              const float* __restrict__ xxall,
                                              float* __restrict__ Dall, int b0) {
    __shared__ float As[16][132];
    __shared__ float Bs[16][132];
    int b = b0 + blockIdx.y;
    const float* X   = Xall + (size_t)b * N_ * C;
    const float* xxb = xxall + (size_t)b * N_;
    float* D = Dall + (size_t)blockIdx.y * N_ * N_;

    int t = blockIdx.x;                      // linear upper-tri tile id
    int ti = 0;
    while (t >= NTILE - ti) { t -= NTILE - ti; ++ti; }
    int tj = ti + t;
    int row0 = ti * 128, col0 = tj * 128;
    int tid = threadIdx.x;
    int tr = tid >> 4, tc = tid & 15;
    float acc[8][8] = {{0.f}};
    for (int kt = 0; kt < C; kt += 16) {
#pragma unroll
        for (int i = 0; i < 8; ++i) {
            int e = tid + 256 * i;
            int r = e >> 4, kk = e & 15;
            int gk = kt + kk;
            As[kk][r] = (gk < C) ? X[(size_t)(row0 + r) * C + gk] : 0.f;
            Bs[kk][r] = (gk < C) ? X[(size_t)(col0 + r) * C + gk] : 0.f;
        }
        __syncthreads();
#pragma unroll
        for (int kk = 0; kk < 16; ++kk) {
            float a[8], bv[8];
            *(float4*)&a[0]  = *(const float4*)&As[kk][tr * 4];
            *(float4*)&a[4]  = *(const float4*)&As[kk][64 + tr * 4];
            *(float4*)&bv[0] = *(const float4*)&Bs[kk][tc * 4];
            *(float4*)&bv[4] = *(const float4*)&Bs[kk][64 + tc * 4];
#pragma unroll
            for (int i = 0; i < 8; ++i)
#pragma unroll
                for (int j = 0; j < 8; ++j) acc[i][j] += a[i] * bv[j];
        }
        __syncthreads();
    }
    float xc[8], xr[8];
#pragma unroll
    for (int j = 0; j < 4; ++j) {
        xc[j]     = xxb[col0 + tc * 4 + j];
        xc[4 + j] = xxb[col0 + 64 + tc * 4 + j];
        xr[j]     = xxb[row0 + tr * 4 + j];
        xr[4 + j] = xxb[row0 + 64 + tr * 4 + j];
    }
#pragma unroll
    for (int i = 0; i < 8; ++i) {
        int lr = (i < 4) ? (tr * 4 + i) : (64 + tr * 4 + (i - 4));
        float xri = xr[i];
        float4 o0, o1;
        o0.x = xri + xc[0] - 2.f * acc[i][0];
        o0.y = xri + xc[1] - 2.f * acc[i][1];
        o0.z = xri + xc[2] - 2.f * acc[i][2];
        o0.w = xri + xc[3] - 2.f * acc[i][3];
        o1.x = xri + xc[4] - 2.f * acc[i][4];
        o1.y = xri + xc[5] - 2.f * acc[i][5];
        o1.z = xri + xc[6] - 2.f * acc[i][6];
        o1.w = xri + xc[7] - 2.f * acc[i][7];
        float* dp = D + (size_t)(row0 + lr) * N_ + col0;
        *(float4*)(dp + tc * 4)      = o0;
        *(float4*)(dp + 64 + tc * 4) = o1;
    }
    if (ti == tj) return;
    // mirrored store via LDS transpose, 4 passes of 32 dt-rows
    float* tb = &As[0][0];
    for (int p = 0; p < 4; ++p) {
        __syncthreads();
        int h = p >> 1;
        int tclo = (p & 1) * 8;
        if (tc >= tclo && tc < tclo + 8) {
#pragma unroll
            for (int jj = 0; jj < 4; ++jj) {
                int j = h * 4 + jj;
                int cl = h * 64 + tc * 4 + jj - 32 * p;   // 0..31
                float xcj = xc[j];
                float4 vlo, vhi;
                vlo.x = xr[0] + xcj - 2.f * acc[0][j];
                vlo.y = xr[1] + xcj - 2.f * acc[1][j];
                vlo.z = xr[2] + xcj - 2.f * acc[2][j];
                vlo.w = xr[3] + xcj - 2.f * acc[3][j];
                vhi.x = xr[4] + xcj - 2.f * acc[4][j];
                vhi.y = xr[5] + xcj - 2.f * acc[5][j];
                vhi.z = xr[6] + xcj - 2.f * acc[6][j];
                vhi.w = xr[7] + xcj - 2.f * acc[7][j];
                *(float4*)&tb[cl * 132 + tr * 4]      = vlo;
                *(float4*)&tb[cl * 132 + 64 + tr * 4] = vhi;
            }
        }
        __syncthreads();
        int rl  = tid >> 3;
        int c16 = (tid & 7) * 16;
#pragma unroll
        for (int q = 0; q < 4; ++q) {
            float4 v = *(const float4*)&tb[rl * 132 + c16 + q * 4];
            *(float4*)(D + (size_t)(col0 + 32 * p + rl) * N_ + row0 + c16 + q * 4) = v;
        }
    }
}

// ---------- key mapping: monotone f32 -> u32 ----------
__device__ __forceinline__ unsigned mapf(float f) {
    unsigned u = __float_as_uint(f);
    return (u & 0x80000000u) ? ~u : (u | 0x80000000u);
}

// ---------- fused top-20 selection (4 quarters + merge); grid.y = batch in group ----------
__global__ __launch_bounds__(256) void k_sel(const float* __restrict__ Dall,
                                             int* __restrict__ knnIdx, int b0) {
    const unsigned long long SENT = ~0ull;
    const unsigned INV = 0xFFFFFFFFu;
    __shared__ unsigned long long qcs[80];
    const float* Db = Dall + (size_t)blockIdx.y * N_ * N_;
    int* idxout = knnIdx + (size_t)(b0 + blockIdx.y) * N_ * KNN_;
    int ql   = blockIdx.x;
    int wv   = threadIdx.x >> 6;
    int lane = threadIdx.x & 63;
    int gbase = wv * 1024 + lane * 16;
    const float* seg = Db + (size_t)ql * N_ + gbase;

    float4 v4[4];
    v4[0] = *(const float4*)(seg);
    v4[1] = *(const float4*)(seg + 4);
    v4[2] = *(const float4*)(seg + 8);
    v4[3] = *(const float4*)(seg + 12);
    const float* vv = (const float*)v4;

    unsigned b0v = INV, b0i = INV, b1v = INV, b1i = INV;
    unsigned emask = 0;
#pragma unroll
    for (int t = 0; t < 16; ++t) {
        unsigned kv = mapf(vv[t]);
        if (kv < b1v) {
            if (kv < b0v) { b1v = b0v; b1i = b0i; b0v = kv; b0i = (unsigned)(gbase + t); }
            else          { b1v = kv; b1i = (unsigned)(gbase + t); }
        }
    }
    for (int k = 0; k < KNN_; ++k) {
        if (b0i == INV) {
            b1v = INV; b1i = INV;
            for (int t = 0; t < 16; ++t) {
                if ((emask >> t) & 1u) continue;
                unsigned kv = mapf(seg[t]);
                if (kv < b1v) {
                    if (kv < b0v) { b1v = b0v; b1i = b0i; b0v = kv; b0i = (unsigned)(gbase + t); }
                    else          { b1v = kv; b1i = (unsigned)(gbase + t); }
                }
            }
        }
        unsigned m = b0v;
#pragma unroll
        for (int s = 32; s > 0; s >>= 1) {
            unsigned o = (unsigned)__shfl_xor((int)m, s, 64);
            m = (o < m) ? o : m;
        }
        unsigned long long ball = __ballot(b0v == m);
        int owner = __ffsll((long long)ball) - 1;
        unsigned idx = (unsigned)__shfl((int)b0i, owner, 64);
        if (lane == owner) {
            emask |= 1u << (b0i & 15u);
            b0v = b1v; b0i = b1i; b1v = INV; b1i = INV;
        }
        if (lane == 0) qcs[wv * KNN_ + k] = ((unsigned long long)m << 32) | idx;
    }
    __syncthreads();
    if (wv == 0) {
        unsigned long long c0 = qcs[lane];
        unsigned long long c1 = (lane < 16) ? qcs[64 + lane] : SENT;
        if (c1 < c0) { unsigned long long t = c0; c0 = c1; c1 = t; }
        for (int k = 0; k < KNN_; ++k) {
            unsigned long long m = c0;
#pragma unroll
            for (int s = 32; s > 0; s >>= 1) {
                unsigned long long o = (unsigned long long)__shfl_xor((long long)m, s, 64);
                if (o < m) m = o;
            }
            if (m == c0) { c0 = c1; c1 = SENT; }
            if (lane == 0) idxout[ql * KNN_ + k] = (int)(unsigned)m;
        }
    }
}

// ---------- layer-1 fused dist+select (C=3), all batches in one launch ----------
__global__ __launch_bounds__(256) void k_selC3(const float* __restrict__ V,
                                               const float* __restrict__ xx,
                                               int* __restrict__ knnIdx) {
    const unsigned long long SENT = ~0ull;
    const unsigned INV = 0xFFFFFFFFu;
    __shared__ unsigned long long qcs[80];
    int b    = blockIdx.y;
    const float* Xb  = V + (size_t)b * N_ * 3;
    const float* xxb = xx + (size_t)b * N_;
    int* idxout = knnIdx + (size_t)b * N_ * KNN_;
    int q    = blockIdx.x;
    int wv   = threadIdx.x >> 6;
    int lane = threadIdx.x & 63;
    int gbase = wv * 1024 + lane * 16;

    float qx = Xb[q * 3], qy = Xb[q * 3 + 1], qz = Xb[q * 3 + 2];
    float xxq = xxb[q];

    float pts[48];
    const float4* src = (const float4*)(Xb + (size_t)gbase * 3);
#pragma unroll
    for (int t = 0; t < 12; ++t) ((float4*)pts)[t] = src[t];
    float xxm[16];
#pragma unroll
    for (int t = 0; t < 16; ++t) xxm[t] = xxb[gbase + t];

    auto distf = [&](int t) -> float {
        float dot = qx * pts[3 * t];
        dot = fmaf(qy, pts[3 * t + 1], dot);
        dot = fmaf(qz, pts[3 * t + 2], dot);
        return xxq + xxm[t] - 2.f * dot;
    };

    unsigned b0v = INV, b0i = INV, b1v = INV, b1i = INV;
    unsigned emask = 0;
#pragma unroll
    for (int t = 0; t < 16; ++t) {
        unsigned kv = mapf(distf(t));
        if (kv < b1v) {
            if (kv < b0v) { b1v = b0v; b1i = b0i; b0v = kv; b0i = (unsigned)(gbase + t); }
            else          { b1v = kv; b1i = (unsigned)(gbase + t); }
        }
    }
    for (int k = 0; k < KNN_; ++k) {
        if (b0i == INV) {
            b1v = INV; b1i = INV;
            for (int t = 0; t < 16; ++t) {
                if ((emask >> t) & 1u) continue;
                unsigned kv = mapf(distf(t));
                if (kv < b1v) {
                    if (kv < b0v) { b1v = b0v; b1i = b0i; b0v = kv; b0i = (unsigned)(gbase + t); }
                    else          { b1v = kv; b1i = (unsigned)(gbase + t); }
                }
            }
        }
        unsigned m = b0v;
#pragma unroll
        for (int s = 32; s > 0; s >>= 1) {
            unsigned o = (unsigned)__shfl_xor((int)m, s, 64);
            m = (o < m) ? o : m;
        }
        unsigned long long ball = __ballot(b0v == m);
        int owner = __ffsll((long long)ball) - 1;
        unsigned idx = (unsigned)__shfl((int)b0i, owner, 64);
        if (lane == owner) {
            emask |= 1u << (b0i & 15u);
            b0v = b1v; b0i = b1i; b1v = INV; b1i = INV;
        }
        if (lane == 0) qcs[wv * KNN_ + k] = ((unsigned long long)m << 32) | idx;
    }
    __syncthreads();
    if (wv == 0) {
        unsigned long long c0 = qcs[lane];
        unsigned long long c1 = (lane < 16) ? qcs[64 + lane] : SENT;
        if (c1 < c0) { unsigned long long t = c0; c0 = c1; c1 = t; }
        for (int k = 0; k < KNN_; ++k) {
            unsigned long long m = c0;
#pragma unroll
            for (int s = 32; s > 0; s >>= 1) {
                unsigned long long o = (unsigned long long)__shfl_xor((long long)m, s, 64);
                if (o < m) m = o;
            }
            if (m == c0) { c0 = c1; c1 = SENT; }
            if (lane == 0) idxout[q * KNN_ + k] = (int)(unsigned)m;
        }
    }
}

// ---------- fused weight prep ----------
__device__ __forceinline__ void prepP_elem(const float* __restrict__ w,
                                           const float* __restrict__ bias,
                                           int C, int O, float* __restrict__ P,
                                           float* __restrict__ b2, int i) {
    int O2 = 2 * O;
    if (i < O2) b2[i] = (i < O) ? 0.f : bias[i - O];
    if (i >= C * O2) return;
    int k = i / O2, col = i % O2;
    float v;
    if (col < O) v = w[(size_t)col * 2 * C + k];
    else { int o = col - O; v = w[(size_t)o * 2 * C + C + k] - w[(size_t)o * 2 * C + k]; }
    P[i] = v;
}
__device__ __forceinline__ void transp_elem(const float* __restrict__ w, int O, int K,
                                            float* __restrict__ wT, int i) {
    if (i >= O * K) return;
    int k = i / O, o = i % O;
    wT[i] = w[(size_t)o * K + k];
}

__global__ void k_prepall(const float* g1w, const float* g1b,
                          const float* g2w, const float* g2b,
                          const float* g3w, const float* g3b,
                          const float* s1w, const float* s1b,
                          const float* s2w, const float* s2b,
                          const float* s3w, const float* s3b,
                          const float* m1w, const float* m2w, const float* m3w,
                          float* P1, float* P2, float* P3, float* P4, float* P5,
                          float* P6, float* P7, float* P8, float* P9,
                          float* bb1, float* bb2, float* bb3,
                          float* bb4, float* bb5, float* bb6) {
    int i = blockIdx.x * 256 + threadIdx.x;
    switch (blockIdx.y) {
        case 0: prepP_elem(g1w, g1b, 3,   64,  P1, bb1, i); break;
        case 1: prepP_elem(g2w, g2b, 64,  128, P2, bb2, i); break;
        case 2: prepP_elem(g3w, g3b, 128, 256, P3, bb3, i); break;
        case 3: prepP_elem(s1w, s1b, 451, 256, P4, bb4, i); break;
        case 4: prepP_elem(s2w, s2b, 256, 128, P5, bb5, i); break;
        case 5: prepP_elem(s3w, s3b, 128, 64,  P6, bb6, i); break;
        case 6: transp_elem(m1w, 512, 448, P7, i); break;
        case 7: transp_elem(m2w, 256, 512, P8, i); break;
        case 8: transp_elem(m3w, 3,   256, P9, i); break;
    }
}

// ---------- tiled f32 GEMM (large M) ----------
__global__ __launch_bounds__(256) void k_gemm(const float* __restrict__ A, int lda,
                                              const float* __restrict__ Bm,
                                              float* __restrict__ Cm, int ldc,
                                              int M, int N, int K,
                                              const float* __restrict__ bias, int leaky) {
    __shared__ float As[16][68];
    __shared__ float Bs[16][68];
    int tid = threadIdx.x;
    int row0 = blockIdx.y * 64, col0 = blockIdx.x * 64;
    int tr = tid >> 4, tc = tid & 15;
    float acc[4][4] = {{0.f}};
    for (int kt = 0; kt < K; kt += 16) {
#pragma unroll
        for (int i = 0; i < 4; ++i) {
            int e = tid + 256 * i;
            int r = e >> 4, kk = e & 15;
            int gr = row0 + r, gk = kt + kk;
            float v = 0.f;
            if (gr < M && gk < K) v = A[(size_t)gr * lda + gk];
            As[kk][r] = v;
        }
#pragma unroll
        for (int i = 0; i < 4; ++i) {
            int e = tid + 256 * i;
            int kk = e >> 6, c = e & 63;
            int gk = kt + kk, gc = col0 + c;
            float v = 0.f;
            if (gk < K && gc < N) v = Bm[(size_t)gk * N + gc];
            Bs[kk][c] = v;
        }
        __syncthreads();
#pragma unroll
        for (int kk = 0; kk < 16; ++kk) {
            float a[4], bv[4];
            *(float4*)&a[0]  = *(const float4*)&As[kk][tr * 4];
            *(float4*)&bv[0] = *(const float4*)&Bs[kk][tc * 4];
#pragma unroll
            for (int i = 0; i < 4; ++i)
#pragma unroll
                for (int j = 0; j < 4; ++j) acc[i][j] += a[i] * bv[j];
        }
        __syncthreads();
    }
#pragma unroll
    for (int i = 0; i < 4; ++i) {
        int r = row0 + tr * 4 + i;
        if (r >= M) continue;
#pragma unroll
        for (int j = 0; j < 4; ++j) {
            int c = col0 + tc * 4 + j;
            if (c >= N) continue;
            float v = acc[i][j];
            if (bias) v += bias[c];
            if (leaky) v = v >= 0.f ? v : SLOPE * v;
            Cm[(size_t)r * ldc + c] = v;
        }
    }
}

// ---------- small-M GEMM ----------
__global__ __launch_bounds__(256) void k_sgemm(const float* __restrict__ A, int lda,
                                               const float* __restrict__ Bm,
                                               float* __restrict__ Cm, int ldc,
                                               int N, int K,
                                               const float* __restrict__ bias, int leaky) {
    extern __shared__ float Arow[];
    int r   = blockIdx.x;
    int c0  = blockIdx.y * 256;
    int tid = threadIdx.x;
    for (int k = tid; k < K; k += 256) Arow[k] = A[(size_t)r * lda + k];
    __syncthreads();
    int c = c0 + tid;
    if (c >= N) return;
    float acc = bias ? bias[c] : 0.f;
    for (int k = 0; k < K; ++k) acc += Arow[k] * Bm[(size_t)k * N + c];
    if (leaky) acc = acc >= 0.f ? acc : SLOPE * acc;
    Cm[(size_t)r * ldc + c] = acc;
}

// ---------- gather-max epilogue (+ optional fused row-norm) ----------
__global__ void k_gathermax(const float* __restrict__ Y, int O, int R,
                            const int* __restrict__ idx, int kc,
                            float* __restrict__ out, int ldo, int ooff,
                            float* __restrict__ xxout) {
    extern __shared__ int sidx[];
    __shared__ float red[256];
    int br = blockIdx.x;
    int b  = br / R;
    int o  = threadIdx.x;
    if (o < kc) sidx[o] = idx[(size_t)br * kc + o];
    __syncthreads();
    int O2 = 2 * O;
    float z = Y[(size_t)br * O2 + O + o];
    float best = -FLT_MAX;
    for (int k = 0; k < kc; ++k) {
        int m = sidx[k];
        best = fmaxf(best, Y[(size_t)(b * R + m) * O2 + o]);
    }
    float r = z + best;
    r = r >= 0.f ? r : SLOPE * r;
    out[(size_t)br * ldo + ooff + o] = r;
    if (xxout) {
        red[o] = r * r;
        __syncthreads();
        for (int s = blockDim.x >> 1; s > 0; s >>= 1) {
            if (o < s) red[o] += red[o + s];
            __syncthreads();
        }
        if (o == 0) xxout[br] = red[0];
    }
}

// ---------- channel map ----------
__device__ __forceinline__ void chan_map(int b, int c,
                                         const float* Vf, const float* l1,
                                         const float* l2, const float* l3,
                                         const float*& p, int& st) {
    if (c < 3)        { st = 3;   p = Vf + (size_t)b * N_ * 3   + c; }
    else if (c < 67)  { st = 64;  p = l1 + (size_t)b * N_ * 64  + (c - 3); }
    else if (c < 195) { st = 128; p = l2 + (size_t)b * N_ * 128 + (c - 67); }
    else              { st = 256; p = l3 + (size_t)b * N_ * 256 + (c - 195); }
}

// ---------- pooling phase 1 ----------
__global__ __launch_bounds__(256) void k_pool2(const float* __restrict__ Vf,
                                               const float* __restrict__ l1,
                                               const float* __restrict__ l2,
                                               const float* __restrict__ l3,
                                               const float* __restrict__ W,
                                               float* __restrict__ ppool,
                                               float* __restrict__ psw) {
    __shared__ float Wl[SLABN][J_];
    int blk  = blockIdx.x;
    int b    = blk / NSLAB, slab = blk % NSLAB;
    int n0   = slab * SLABN;
    int tid  = threadIdx.x;

    for (int e = tid; e < J_ * SLABN; e += 256) {
        int j = e / SLABN, n = e % SLABN;
        Wl[n][j] = W[((size_t)b * J_ + j) * N_ + n0 + n];
    }
    __syncthreads();

    if (tid < J_) {
        float s = 0.f;
        for (int n = 0; n < SLABN; ++n) s += Wl[n][tid];
        psw[(size_t)blk * J_ + tid] = s;
    }

    int c0 = tid, c1 = tid + 256;
    const float *p0, *p1 = nullptr; int s0, s1 = 0;
    chan_map(b, c0, Vf, l1, l2, l3, p0, s0);
    bool has1 = (c1 < 451);
    if (has1) chan_map(b, c1, Vf, l1, l2, l3, p1, s1);

    float acc0[J_], acc1[J_];
#pragma unroll
    for (int j = 0; j < J_; ++j) { acc0[j] = 0.f; acc1[j] = 0.f; }

    for (int n = 0; n < SLABN; ++n) {
        float v0 = p0[(size_t)(n0 + n) * s0];
        float v1 = has1 ? p1[(size_t)(n0 + n) * s1] : 0.f;
        const float* wn = &Wl[n][0];
#pragma unroll
        for (int q = 0; q < J_ / 4; ++q) {
            float4 w4 = *(const float4*)(wn + 4 * q);
            acc0[4*q+0] += w4.x * v0;  acc1[4*q+0] += w4.x * v1;
            acc0[4*q+1] += w4.y * v0;  acc1[4*q+1] += w4.y * v1;
            acc0[4*q+2] += w4.z * v0;  acc1[4*q+2] += w4.z * v1;
            acc0[4*q+3] += w4.w * v0;  acc1[4*q+3] += w4.w * v1;
        }
    }
    float* pp = ppool + (size_t)blk * J_ * 451;
#pragma unroll
    for (int j = 0; j < J_; ++j) {
        pp[(size_t)j * 451 + c0] = acc0[j];
        if (has1) pp[(size_t)j * 451 + c1] = acc1[j];
    }
}

// ---------- pooling phase 2 ----------
__global__ __launch_bounds__(256) void k_poolred(const float* __restrict__ ppool,
                                                 const float* __restrict__ psw,
                                                 float* __restrict__ pooled) {
    int bj = blockIdx.x;
    int b  = bj / J_, j = bj % J_;
    int tid = threadIdx.x;

    float sw = 0.f;
    for (int sl = 0; sl < NSLAB; ++sl) sw += psw[(size_t)(b * NSLAB + sl) * J_ + j];
    float inv = 1.f / (sw + 1e-5f);

    for (int c = tid; c < 451; c += 256) {
        float s = 0.f;
        for (int sl = 0; sl < NSLAB; ++sl)
            s += ppool[((size_t)(b * NSLAB + sl) * J_ + j) * 451 + c];
        pooled[(size_t)bj * 451 + c] = s * inv;
    }
}

extern "C" void kernel_launch(void* const* d_in, const int* in_sizes, int n_in,
                              void* d_out, int out_size, void* d_ws, size_t ws_size,
                              hipStream_t stream) {
    const float* V  = (const float*)d_in[0];
    const float* W  = (const float*)d_in[1];
    const int* ringIdx = (const int*)d_in[2];
    const float* g1w = (const float*)d_in[3];
    const float* g1b = (const float*)d_in[4];
    const float* g2w = (const float*)d_in[5];
    const float* g2b = (const float*)d_in[6];
    const float* g3w = (const float*)d_in[7];
    const float* g3b = (const float*)d_in[8];
    const float* s1w = (const float*)d_in[9];
    const float* s1b = (const float*)d_in[10];
    const float* s2w = (const float*)d_in[11];
    const float* s2b = (const float*)d_in[12];
    const float* s3w = (const float*)d_in[13];
    const float* s3b = (const float*)d_in[14];
    const float* m1w = (const float*)d_in[15];
    const float* m1b = (const float*)d_in[16];
    const float* m2w = (const float*)d_in[17];
    const float* m2b = (const float*)d_in[18];
    const float* m3w = (const float*)d_in[19];
    const float* m3b = (const float*)d_in[20];
    (void)n_in; (void)in_sizes; (void)out_size;

    const int szP1 = 3 * 128,    szP2 = 64 * 256,  szP3 = 128 * 512;
    const int szP4 = 451 * 512,  szP5 = 256 * 256, szP6 = 128 * 128;
    const int szP7 = 448 * 512,  szP8 = 512 * 256, szP9 = 256 * 3;

    // ---- bytes needed for nd D-buffers (rest of layout fixed) ----
    auto layout_bytes = [&](int nd) -> size_t {
        size_t f = 0;
        f += (size_t)B_ * N_ * 64 + (size_t)B_ * N_ * 128 + (size_t)B_ * N_ * 256;
        f += (size_t)B_ * N_;                         // xx
        f += (size_t)nd * N_ * N_;                    // D buffers
        f += (size_t)B_ * N_ * KNN_;                  // knnIdx (ints)
        f += (size_t)B_ * J_ * 451 + (size_t)B_ * J_ * 448;
        f += (size_t)B_ * J_ * 512 + (size_t)B_ * J_ * 256;
        f += (size_t)(szP1 + szP2 + szP3 + szP4 + szP5 + szP6 + szP7 + szP8 + szP9);
        f += 128 + 256 + 512 + 512 + 256 + 128;
        return f * 4;
    };
    // nb = batches per dist/sel group (deterministic in ws_size -> graph-safe)
    int nb = 1;
    if (ws_size >= layout_bytes(4)) nb = 4;
    else if (ws_size >= layout_bytes(2)) nb = 2;

    // ---- workspace layout (floats) ----
    float* ws = (float*)d_ws;
    size_t off = 0;
    float* l1 = ws + off; off += (size_t)B_ * N_ * 64;
    float* l2 = ws + off; off += (size_t)B_ * N_ * 128;
    float* l3 = ws + off; off += (size_t)B_ * N_ * 256;
    float* xx = ws + off; off += (size_t)B_ * N_;
    float* D  = ws + off; off += (size_t)nb * N_ * N_;   // nb D buffers
    float* Y  = D;                                        // 32 MB <= first D buffer
    float* ppool = D;
    float* psw   = D + (size_t)B_ * NSLAB * J_ * 451;
    int* knnIdx = (int*)(ws + off); off += (size_t)B_ * N_ * KNN_;
    float* pooled = ws + off; off += (size_t)B_ * J_ * 451;
    float* joints = ws + off; off += (size_t)B_ * J_ * 448;
    float* h1 = ws + off; off += (size_t)B_ * J_ * 512;
    float* h2 = ws + off; off += (size_t)B_ * J_ * 256;
    float* P1 = ws + off; off += szP1;
    float* P2 = ws + off; off += szP2;
    float* P3 = ws + off; off += szP3;
    float* P4 = ws + off; off += szP4;
    float* P5 = ws + off; off += szP5;
    float* P6 = ws + off; off += szP6;
    float* P7 = ws + off; off += szP7;
    float* P8 = ws + off; off += szP8;
    float* P9 = ws + off; off += szP9;
    float* bb1 = ws + off; off += 128;
    float* bb2 = ws + off; off += 256;
    float* bb3 = ws + off; off += 512;
    float* bb4 = ws + off; off += 512;
    float* bb5 = ws + off; off += 256;
    float* bb6 = ws + off; off += 128;

    const int M = B_ * N_;   // 16384
    const int MJ = B_ * J_;  // 96
    const int NUTRI = NTILE * (NTILE + 1) / 2;   // 528 upper-tri tiles

    // ---- all weight prep in one launch ----
    k_prepall<<<dim3((szP4 + 255) / 256, 9), 256, 0, stream>>>(
        g1w, g1b, g2w, g2b, g3w, g3b, s1w, s1b, s2w, s2b, s3w, s3b,
        m1w, m2w, m3w, P1, P2, P3, P4, P5, P6, P7, P8, P9,
        bb1, bb2, bb3, bb4, bb5, bb6);

    // ======== geoNet layer 1: C=3 -> O=64 (fused dist+select) ========
    k_norm<<<(M + 255) / 256, 256, 0, stream>>>(V, xx, 3);
    k_selC3<<<dim3(N_, B_), 256, 0, stream>>>(V, xx, knnIdx);
    k_gemm<<<dim3(2, M / 64), 256, 0, stream>>>(V, 3, P1, Y, 128, M, 128, 3, bb1, 0);
    k_gathermax<<<M, 64, KNN_ * sizeof(int), stream>>>(Y, 64, N_, knnIdx, KNN_, l1, 64, 0, xx);

    // ======== layer 2: C=64 -> O=128 ========
    for (int g = 0; g < B_; g += nb) {
        k_dist<<<dim3(NUTRI, nb), 256, 0, stream>>>(l1, 64, xx, D, g);
        k_sel<<<dim3(N_, nb), 256, 0, stream>>>(D, knnIdx, g);
    }
    k_gemm<<<dim3(4, M / 64), 256, 0, stream>>>(l1, 64, P2, Y, 256, M, 256, 64, bb2, 0);
    k_gathermax<<<M, 128, KNN_ * sizeof(int), stream>>>(Y, 128, N_, knnIdx, KNN_, l2, 128, 0, xx);

    // ======== layer 3: C=128 -> O=256 ========
    for (int g = 0; g < B_; g += nb) {
        k_dist<<<dim3(NUTRI, nb), 256, 0, stream>>>(l2, 128, xx, D, g);
        k_sel<<<dim3(N_, nb), 256, 0, stream>>>(D, knnIdx, g);
    }
    k_gemm<<<dim3(8, M / 64), 256, 0, stream>>>(l2, 128, P3, Y, 512, M, 512, 128, bb3, 0);
    k_gathermax<<<M, 256, KNN_ * sizeof(int), stream>>>(Y, 256, N_, knnIdx, KNN_, l3, 256, 0, nullptr);

    // ======== pooling onto joints ========
    k_pool2<<<B_ * NSLAB, 256, 0, stream>>>(V, l1, l2, l3, W, ppool, psw);
    k_poolred<<<MJ, 256, 0, stream>>>(ppool, psw, pooled);

    // ======== skeleton convs ========
    k_sgemm<<<dim3(MJ, 2), 256, 451 * sizeof(float), stream>>>(pooled, 451, P4, Y, 512, 512, 451, bb4, 0);
    k_gathermax<<<MJ, 256, KR_ * sizeof(int), stream>>>(Y, 256, J_, ringIdx, KR_, joints, 448, 0, nullptr);

    k_sgemm<<<dim3(MJ, 1), 256, 256 * sizeof(float), stream>>>(joints, 448, P5, Y, 256, 256, 256, bb5, 0);
    k_gathermax<<<MJ, 128, KR_ * sizeof(int), stream>>>(Y, 128, J_, ringIdx, KR_, joints, 448, 256, nullptr);

    k_sgemm<<<dim3(MJ, 1), 256, 128 * sizeof(float), stream>>>(joints + 256, 448, P6, Y, 128, 128, 128, bb6, 0);
    k_gathermax<<<MJ, 64, KR_ * sizeof(int), stream>>>(Y, 64, J_, ringIdx, KR_, joints, 448, 384, nullptr);

    // ======== joint MLP ========
    k_sgemm<<<dim3(MJ, 2), 256, 448 * sizeof(float), stream>>>(joints, 448, P7, h1, 512, 512, 448, m1b, 1);
    k_sgemm<<<dim3(MJ, 1), 256, 512 * sizeof(float), stream>>>(h1, 512, P8, h2, 256, 256, 512, m2b, 1);
    k_sgemm<<<dim3(MJ, 1), 256, 256 * sizeof(float), stream>>>(h2, 256, P9, (float*)d_out, 3, 3, 256, m3b, 0);
}